// Round 5
// baseline (1645.945 us; speedup 1.0000x reference)
//
#include <hip/hip_runtime.h>
#include <hip/hip_bf16.h>

typedef unsigned short u16;
typedef __bf16 bf16x8 __attribute__((ext_vector_type(8)));
typedef float  f32x4  __attribute__((ext_vector_type(4)));

#define N_  16384
#define SCALE_ 0.125f
#define TILE 128
#define TPAD 66
#define AP6 136   // atb row stride (u16): 272B, 16B-aligned

__device__ __forceinline__ u16 f2b(float f){
  unsigned u = __float_as_uint(f);
  unsigned r = (u + 0x7fffu + ((u>>16)&1u)) >> 16;
  return (u16)r;
}
__device__ __forceinline__ float blo(unsigned u){ return __uint_as_float(u<<16); }
__device__ __forceinline__ float bhi(unsigned u){ return __uint_as_float(u & 0xffff0000u); }
__device__ __forceinline__ float b2f(u16 v){ return __uint_as_float(((unsigned)v)<<16); }
__device__ __forceinline__ void ld8(const float* __restrict__ p, float* f){
  const float4 a = ((const float4*)p)[0];
  const float4 b = ((const float4*)p)[1];
  f[0]=a.x; f[1]=a.y; f[2]=a.z; f[3]=a.w;
  f[4]=b.x; f[5]=b.y; f[6]=b.z; f[7]=b.w;
}
__device__ __forceinline__ bf16x8 frag8(const float* __restrict__ p){
  float f[8]; ld8(p, f);
  bf16x8 r;
  #pragma unroll
  for (int j=0;j<8;++j) r[j] = (__bf16)f[j];
  return r;
}

// ---------------- diagnostic marker (fp32 out) ----------------
__global__ __launch_bounds__(256) void k_marker(float* __restrict__ out, int n, float val){
  const int i = blockIdx.x*256 + threadIdx.x;
  if (i < n) out[i] = val;
}

// ---------------- shared helper: slots row -> q (and qk, q.bk) ----------------
__device__ __forceinline__ void q_from_slots(
  const float sv, const int ri, const int lane,
  const float* __restrict__ Wq, const float* __restrict__ bq,
  const float* __restrict__ g_sl, const float* __restrict__ b_sl,
  const float* __restrict__ wkT, const float* __restrict__ bk,
  float* __restrict__ qout, float* __restrict__ qkb, float* __restrict__ qbb,
  const int do_qk)
{
  float s = sv, ss = sv*sv;
  #pragma unroll
  for (int off=1; off<64; off<<=1){ s += __shfl_xor(s,off); ss += __shfl_xor(ss,off); }
  const float mean = s*(1.f/64.f);
  const float rstd = rsqrtf(ss*(1.f/64.f) - mean*mean + 1e-5f);
  const float sn = (sv-mean)*rstd*g_sl[lane] + b_sl[lane];
  float acc = 0.f;
  for (int d8=0; d8<8; ++d8){
    float wf[8]; ld8(Wq + lane*64 + d8*8, wf);
    #pragma unroll
    for (int j=0;j<8;++j) acc += __shfl(sn, d8*8+j) * wf[j];
  }
  const float qv = acc + bq[lane];
  qout[ri*64+lane] = qv;
  if (do_qk){
    float pb = qv * bk[lane];
    #pragma unroll
    for (int off=1; off<64; off<<=1) pb += __shfl_xor(pb, off);
    if (lane == 0) qbb[ri] = pb;
    float qkv = 0.f;
    for (int d8=0; d8<8; ++d8){
      float wf[8]; ld8(wkT + lane*64 + d8*8, wf);
      #pragma unroll
      for (int j=0;j<8;++j) qkv += __shfl(qv, d8*8+j) * wf[j];
    }
    qkb[ri*64+lane] = qkv;
  }
}

// ---------------- shared helper: one GRU+MLP row (full wave) ----------------
__device__ __forceinline__ float gru_mlp_row(
  const float u, const float h, const int lane,
  const float* __restrict__ Wih, const float* __restrict__ Whh,
  const float* __restrict__ bih, const float* __restrict__ bhh,
  const float* __restrict__ mW1, const float* __restrict__ mb1,
  const float* __restrict__ mW2, const float* __restrict__ mb2,
  const float* __restrict__ g_ml, const float* __restrict__ b_ml)
{
  float air=0,aiz=0,ain=0,ahr=0,ahz=0,ahn=0;
  for (int d8=0; d8<8; ++d8){
    float fir[8],fiz[8],fin[8],fhr[8],fhz[8],fhn[8];
    ld8(Wih + (      lane)*64 + d8*8, fir);
    ld8(Wih + ( 64 + lane)*64 + d8*8, fiz);
    ld8(Wih + (128 + lane)*64 + d8*8, fin);
    ld8(Whh + (      lane)*64 + d8*8, fhr);
    ld8(Whh + ( 64 + lane)*64 + d8*8, fhz);
    ld8(Whh + (128 + lane)*64 + d8*8, fhn);
    #pragma unroll
    for (int j=0;j<8;++j){
      const float ud = __shfl(u, d8*8+j);
      const float hd = __shfl(h, d8*8+j);
      air += ud*fir[j]; aiz += ud*fiz[j]; ain += ud*fin[j];
      ahr += hd*fhr[j]; ahz += hd*fhz[j]; ahn += hd*fhn[j];
    }
  }
  air += bih[lane]; aiz += bih[64+lane]; ain += bih[128+lane];
  ahr += bhh[lane]; ahz += bhh[64+lane]; ahn += bhh[128+lane];
  const float r = 1.f/(1.f + __expf(-(air+ahr)));
  const float z = 1.f/(1.f + __expf(-(aiz+ahz)));
  const float n = tanhf(ain + r*ahn);
  const float sv = (1.f-z)*n + z*h;
  float s=sv, ss=sv*sv;
  #pragma unroll
  for (int off=1; off<64; off<<=1){ s += __shfl_xor(s,off); ss += __shfl_xor(ss,off); }
  const float mean = s*(1.f/64.f);
  const float rstd = rsqrtf(ss*(1.f/64.f) - mean*mean + 1e-5f);
  const float m = (sv-mean)*rstd*g_ml[lane] + b_ml[lane];
  float h1a=0.f, h1b=0.f;
  for (int d8=0; d8<8; ++d8){
    float f1[8], f2[8];
    ld8(mW1 + (     lane)*64 + d8*8, f1);
    ld8(mW1 + (64 + lane)*64 + d8*8, f2);
    #pragma unroll
    for (int j=0;j<8;++j){
      const float md = __shfl(m, d8*8+j);
      h1a += md*f1[j]; h1b += md*f2[j];
    }
  }
  h1a = fmaxf(h1a + mb1[lane], 0.f);
  h1b = fmaxf(h1b + mb1[64+lane], 0.f);
  float o = 0.f;
  for (int h8=0; h8<8; ++h8){
    float fa[8], fb[8];
    ld8(mW2 + lane*128 + h8*8, fa);
    ld8(mW2 + lane*128 + 64 + h8*8, fb);
    #pragma unroll
    for (int j=0;j<8;++j){
      o += __shfl(h1a, h8*8+j)*fa[j] + __shfl(h1b, h8*8+j)*fb[j];
    }
  }
  o += mb2[lane];
  return sv + o;
}

// ---------------- slots init (+ first q, + zero num/den/counters) ----------------
__global__ __launch_bounds__(256) void k_init_slots_q(
  const float* __restrict__ mu, const float* __restrict__ sigma,
  const float* __restrict__ noise, float* __restrict__ slots,
  const float* __restrict__ Wq, const float* __restrict__ bq,
  const float* __restrict__ g_sl, const float* __restrict__ b_sl,
  const float* __restrict__ wkT, const float* __restrict__ bk,
  float* __restrict__ qout, float* __restrict__ qkb, float* __restrict__ qbb,
  float* __restrict__ num, float* __restrict__ den, int* __restrict__ cnt2,
  const int do_qk)
{
  const int tid = blockIdx.x*256 + threadIdx.x;   // grid 56*256 = 14336 exact
  const int ri = tid>>6, lane = tid&63;
  const float sv = mu[lane] + sigma[lane] * noise[tid];
  slots[tid] = sv;
  num[tid] = 0.f;
  if (tid < 224) den[tid] = 0.f;
  if (tid < 64) cnt2[tid] = 0;                    // both finisher counter arrays
  q_from_slots(sv, ri, lane, Wq, bq, g_sl, b_sl, wkT, bk, qout, qkb, qbb, do_qk);
}

// ---------------- Wk transpose: wkT[e][d] = Wk[d][e] (once) ----------------
__global__ __launch_bounds__(256) void k_wkt(const float* __restrict__ Wk, float* __restrict__ wkT){
  const int i = blockIdx.x*256 + threadIdx.x;     // grid 16*256 = 4096 exact
  const int e = i>>6, d = i&63;
  wkT[i] = Wk[d*64 + e];
}

// ---------------- xln: LayerNorm(inputs) -> bf16, row-major ----------------
__global__ __launch_bounds__(256) void k_xln(
  const float* __restrict__ x, const float* __restrict__ g_in, const float* __restrict__ b_in,
  u16* __restrict__ xout)
{
  const int t = threadIdx.x;
  const long blk = blockIdx.x;
  const float4 gv = *(const float4*)(g_in + (t&15)*4);
  const float4 bb = *(const float4*)(b_in + (t&15)*4);
  const float* xbase = x + blk*16384;       // 256 rows * 64 f
  u16* obase = xout + blk*16384;
  float4 v[16];
  #pragma unroll
  for (int p=0;p<16;++p) v[p] = *(const float4*)(xbase + p*1024 + t*4);
  #pragma unroll
  for (int p=0;p<16;++p){
    float s = v[p].x + v[p].y + v[p].z + v[p].w;
    float q = v[p].x*v[p].x + v[p].y*v[p].y + v[p].z*v[p].z + v[p].w*v[p].w;
    #pragma unroll
    for (int off=1; off<16; off<<=1){ s += __shfl_xor(s, off); q += __shfl_xor(q, off); }
    const float mean = s*(1.f/64.f);
    const float rstd = rsqrtf(q*(1.f/64.f) - mean*mean + 1e-5f);
    const u16 e0 = f2b((v[p].x-mean)*rstd*gv.x + bb.x);
    const u16 e1 = f2b((v[p].y-mean)*rstd*gv.y + bb.y);
    const u16 e2 = f2b((v[p].z-mean)*rstd*gv.z + bb.z);
    const u16 e3 = f2b((v[p].w-mean)*rstd*gv.w + bb.w);
    const unsigned w0 = (unsigned)e0 | ((unsigned)e1<<16);
    const unsigned w1 = (unsigned)e2 | ((unsigned)e3<<16);
    *(uint2*)(obase + p*1024 + t*4) = make_uint2(w0, w1);
  }
}

// ================= FAST PATH: MFMA streaming attention v7 + fused GRU finisher ====
// grid = 32 b x 128 ch (128 keys/block). Plain-store partials; the last block
// of each batch (device atomic counter) reduces them and runs GRU/MLP/q for
// that batch's 7 slot rows. No standalone k_gru_mlp dispatch in fast mode.
__global__ __launch_bounds__(256, 5) void k_attn7(
  const u16* __restrict__ xln, const float* __restrict__ qkb_in, const float* __restrict__ qbb_in,
  float* __restrict__ pnum, float* __restrict__ pden, int* __restrict__ cnt,
  float* __restrict__ slots,
  const float* __restrict__ Wv, const float* __restrict__ bv,
  const float* __restrict__ Wih, const float* __restrict__ Whh,
  const float* __restrict__ bih, const float* __restrict__ bhh,
  const float* __restrict__ mW1, const float* __restrict__ mb1,
  const float* __restrict__ mW2, const float* __restrict__ mb2,
  const float* __restrict__ g_ml, const float* __restrict__ b_ml,
  const float* __restrict__ Wq, const float* __restrict__ bq,
  const float* __restrict__ g_sl, const float* __restrict__ b_sl,
  const float* __restrict__ wkT, const float* __restrict__ bk,
  float* __restrict__ qout, float* __restrict__ qkb_out, float* __restrict__ qbb_out,
  float* __restrict__ outp, const int write_out, const int do_q)
{
  __shared__ __align__(16) u16   xs[128*64];      // 16 KB swizzled x̂ tile
  __shared__ __align__(16) u16   atb[7*AP6];      // bf16 attn weights
  __shared__ __align__(16) float dlds[128*9];     // dots (stride-9 pad)
  __shared__ float qbs[7];
  __shared__ float den_s[7];
  __shared__ int isLast;
  const int t = threadIdx.x;
  const int b = blockIdx.x >> 7, ch = blockIdx.x & 127;
  const int wid = t>>6, lane = t&63;
  const int m15 = lane&15, g4 = lane>>4;

  // stage x̂ tile (128 keys x 64 dims): 4 x b128 per thread
  const u16* gbase = xln + ((long)b*N_ + ch*128)*64;
  uint4 st[4];
  #pragma unroll
  for (int p=0;p<4;++p) st[p] = *(const uint4*)(gbase + p*2048 + t*8);
  if (t < 7){ qbs[t] = qbb_in[b*7+t]; den_s[t] = 0.f; }
  // qk B-frags (slot n = m15, dims f*32 + g4*8 + j), slots 7..15 zero
  bf16x8 qf[2];
  #pragma unroll
  for (int f=0; f<2; ++f){
    float tmp[8];
    if (m15 < 7){ ld8(qkb_in + b*448 + m15*64 + f*32 + g4*8, tmp); }
    else {
      #pragma unroll
      for (int j=0;j<8;++j) tmp[j]=0.f;
    }
    #pragma unroll
    for (int j=0;j<8;++j) qf[f][j] = (__bf16)tmp[j];
  }
  #pragma unroll
  for (int p=0;p<4;++p)
    *(uint4*)&xs[(p*32 + (t>>3))*64 + (((t&7) ^ ((t>>3)&7))<<3)] = st[p];
  __syncthreads();

  // ---- phase A: dots[key][slot] via MFMA ----
  #pragma unroll
  for (int mt=0; mt<2; ++mt){
    const int kr = (wid<<5) + (mt<<4) + m15;      // A: m=key
    f32x4 dacc = {0.f,0.f,0.f,0.f};
    #pragma unroll
    for (int f=0; f<2; ++f){
      const int c = (f<<2) + g4;                  // 16B chunk = dim/8
      const uint4 aw = *(const uint4*)&xs[kr*64 + ((c ^ (kr&7))<<3)];
      dacc = __builtin_amdgcn_mfma_f32_16x16x32_bf16(
               __builtin_bit_cast(bf16x8, aw), qf[f], dacc, 0,0,0);
    }
    if (m15 < 7){                                 // C: col=slot, row=key in 16
      const int krow = (wid<<5) + (mt<<4) + (g4<<2);
      #pragma unroll
      for (int r=0;r<4;++r) dlds[(krow+r)*9 + m15] = dacc[r];
    }
  }
  __syncthreads();

  // ---- per-key softmax over 7 slots (threads 0..127) ----
  if (t < 128){
    float acc[7];
    #pragma unroll
    for (int i=0;i<7;++i) acc[i] = (dlds[t*9+i] + qbs[i]) * SCALE_;
    float mx = -1e30f;
    #pragma unroll
    for (int i=0;i<7;++i) mx = fmaxf(mx, acc[i]);
    float e[7]; float sum = 0.f;
    #pragma unroll
    for (int i=0;i<7;++i){ e[i] = __expf(acc[i]-mx); sum += e[i]; }
    const float inv = 1.f/sum;
    float dsum[7];
    #pragma unroll
    for (int i=0;i<7;++i){
      const u16 rb = f2b(e[i]*inv + 1e-8f);
      atb[i*AP6 + t] = rb;
      dsum[i] = b2f(rb);            // den from the SAME rounded weights as num
    }
    #pragma unroll
    for (int i=0;i<7;++i){
      #pragma unroll
      for (int off=1; off<64; off<<=1) dsum[i] += __shfl_xor(dsum[i], off);
    }
    if (lane == 0){
      #pragma unroll
      for (int i=0;i<7;++i) atomicAdd(&den_s[i], dsum[i]);   // LDS atomic only
    }
  }
  __syncthreads();

  // ---- phase B: num^T[dim][slot] += x̂^T[dim][key] @ attn^T[key][slot] ----
  const int dim2 = ((wid<<4) + m15) << 1;   // byte col of this lane's A-dim
  f32x4 accv = {0.f,0.f,0.f,0.f};
  #pragma unroll
  for (int ks=0; ks<4; ++ks){
    const int kbase = (ks<<5) + (g4<<3);    // key base, multiple of 8
    const unsigned a0 = xs[(kbase+0)*64 + ((dim2 ^ (0<<4))>>1)];
    const unsigned a1 = xs[(kbase+1)*64 + ((dim2 ^ (1<<4))>>1)];
    const unsigned a2 = xs[(kbase+2)*64 + ((dim2 ^ (2<<4))>>1)];
    const unsigned a3 = xs[(kbase+3)*64 + ((dim2 ^ (3<<4))>>1)];
    const unsigned a4 = xs[(kbase+4)*64 + ((dim2 ^ (4<<4))>>1)];
    const unsigned a5 = xs[(kbase+5)*64 + ((dim2 ^ (5<<4))>>1)];
    const unsigned a6 = xs[(kbase+6)*64 + ((dim2 ^ (6<<4))>>1)];
    const unsigned a7 = xs[(kbase+7)*64 + ((dim2 ^ (7<<4))>>1)];
    const uint4 aw = make_uint4(a0|(a1<<16), a2|(a3<<16), a4|(a5<<16), a6|(a7<<16));
    const bf16x8 af = __builtin_bit_cast(bf16x8, aw);
    uint4 bw = make_uint4(0u,0u,0u,0u);
    if (m15 < 7) bw = *(const uint4*)&atb[m15*AP6 + kbase];
    const bf16x8 bfv = __builtin_bit_cast(bf16x8, bw);
    accv = __builtin_amdgcn_mfma_f32_16x16x32_bf16(af, bfv, accv, 0,0,0);
  }

  // ---- plain-store partials (no atomics) ----
  if (m15 < 7){
    float* np = &pnum[(((long)b*7 + m15)*128 + ch)*64 + (wid<<4) + (g4<<2)];
    #pragma unroll
    for (int r=0;r<4;++r) np[r] = accv[r];
  }
  if (t < 7) pden[(b*7+t)*128 + ch] = den_s[t];

  // ---- last-block finisher: reduce partials + GRU/MLP/q for batch b ----
  __syncthreads();                      // drains vmcnt: all stores left the CU
  if (t == 0){
    __threadfence();                    // release: flush to device scope
    isLast = (atomicAdd(&cnt[b], 1) == 127);
  }
  __syncthreads();
  if (!isLast) return;
  __threadfence();                      // acquire: invalidate local caches
  if (t == 0) cnt[b] = 0;               // reset for reuse by iter 2

  for (int s = wid; s < 7; s += 4){     // wave w -> rows w, w+4
    const int ri = b*7 + s;
    // reduce 128 partials
    float asum = 0.f;
    const float* pn = pnum + (long)ri*8192 + lane;
    #pragma unroll 8
    for (int c=0;c<128;++c) asum += pn[c*64];
    float v = pden[ri*128 + lane] + pden[ri*128 + 64 + lane];
    #pragma unroll
    for (int off=1; off<64; off<<=1) v += __shfl_xor(v, off);
    const float dn = v;
    const float a = (dn > 0.f) ? (asum / dn) : 0.f;
    // u = a @ Wv^T + bv
    float uacc = 0.f;
    for (int e8=0; e8<8; ++e8){
      float f[8]; ld8(Wv + lane*64 + e8*8, f);
      #pragma unroll
      for (int j=0;j<8;++j) uacc += __shfl(a, e8*8+j) * f[j];
    }
    const float u = uacc + bv[lane];
    const float h = slots[ri*64+lane];
    const float res = gru_mlp_row(u, h, lane, Wih, Whh, bih, bhh,
                                  mW1, mb1, mW2, mb2, g_ml, b_ml);
    slots[ri*64+lane] = res;
    if (write_out) outp[ri*64+lane] = res;
    if (do_q)
      q_from_slots(res, ri, lane, Wq, bq, g_sl, b_sl, wkT, bk,
                   qout, qkb_out, qbb_out, 1);
  }
}

// ================= FALLBACK: fused attention (verified) =================
__global__ __launch_bounds__(256) void k_attn_fused(
  const float* __restrict__ x,
  const float* __restrict__ Wk, const float* __restrict__ bk,
  const float* __restrict__ Wv, const float* __restrict__ bv,
  const float* __restrict__ g_in, const float* __restrict__ b_in,
  const float* __restrict__ qbuf, float* __restrict__ num, float* __restrict__ den)
{
  __shared__ __align__(16) u16   tile[TILE*TPAD];
  __shared__ __align__(16) float qs[7*64];
  __shared__ __align__(16) float at[7*TILE];
  const int t = threadIdx.x;
  const int b = blockIdx.x >> 6, ch = blockIdx.x & 63;
  for (int i=t; i<448; i+=256) qs[i] = qbuf[b*448 + i];
  const int wid = t>>6, lane = t&63;
  const int m = lane & 15, q4 = lane >> 4;
  float gf[16], bfv[16];
  ld8(g_in + q4*8, gf);  ld8(g_in + 32 + q4*8, gf+8);
  ld8(b_in + q4*8, bfv); ld8(b_in + 32 + q4*8, bfv+8);
  const int i0 = wid*2, i1 = wid*2+1;
  float n0=0.f, n1=0.f, d0=0.f, d1=0.f;

  for (int tl=0; tl<2; ++tl){
    const long j0 = (long)ch*256 + tl*TILE;
    const long rowbase = (long)b*N_ + j0 + (long)wid*32;
    __syncthreads();
    bf16x8 af[2][2];
    #pragma unroll
    for (int rg=0; rg<2; ++rg){
      const float* xr = x + (rowbase + rg*16 + m)*64;
      float xf[16];
      ld8(xr + q4*8, xf); ld8(xr + 32 + q4*8, xf+8);
      float s=0.f, ss=0.f;
      #pragma unroll
      for (int i=0;i<16;++i){ s += xf[i]; ss += xf[i]*xf[i]; }
      s  += __shfl_xor(s,16);  s  += __shfl_xor(s,32);
      ss += __shfl_xor(ss,16); ss += __shfl_xor(ss,32);
      const float mean = s*(1.f/64.f);
      const float rstd = rsqrtf(ss*(1.f/64.f) - mean*mean + 1e-5f);
      #pragma unroll
      for (int j=0;j<8;++j){
        af[rg][0][j] = (__bf16)((xf[j]  -mean)*rstd*gf[j]   + bfv[j]);
        af[rg][1][j] = (__bf16)((xf[8+j]-mean)*rstd*gf[8+j] + bfv[8+j]);
      }
    }
    {
      bf16x8 w0[4], w1[4]; float bc[4];
      #pragma unroll
      for (int cg=0; cg<4; ++cg){
        const int n = cg*16 + m;
        w0[cg] = frag8(Wk + n*64 + q4*8);
        w1[cg] = frag8(Wk + n*64 + 32 + q4*8);
        bc[cg] = bk[n];
      }
      #pragma unroll
      for (int rg=0; rg<2; ++rg){
        #pragma unroll
        for (int cg=0; cg<4; ++cg){
          f32x4 acc = {0.f,0.f,0.f,0.f};
          acc = __builtin_amdgcn_mfma_f32_16x16x32_bf16(af[rg][0], w0[cg], acc, 0,0,0);
          acc = __builtin_amdgcn_mfma_f32_16x16x32_bf16(af[rg][1], w1[cg], acc, 0,0,0);
          const int col = cg*16 + m;
          #pragma unroll
          for (int r=0;r<4;++r)
            tile[(wid*32 + rg*16 + q4*4 + r)*TPAD + col] = f2b(acc[r] + bc[cg]);
        }
      }
    }
    __syncthreads();
    if (t < TILE){
      float acc[7];
      #pragma unroll
      for (int i=0;i<7;++i) acc[i]=0.f;
      const unsigned* krow = (const unsigned*)&tile[t*TPAD];
      for (int wq=0; wq<8; ++wq){
        const unsigned k0 = krow[wq*4+0], k1 = krow[wq*4+1], k2 = krow[wq*4+2], k3 = krow[wq*4+3];
        float kf[8];
        kf[0]=blo(k0); kf[1]=bhi(k0); kf[2]=blo(k1); kf[3]=bhi(k1);
        kf[4]=blo(k2); kf[5]=bhi(k2); kf[6]=blo(k3); kf[7]=bhi(k3);
        #pragma unroll
        for (int i=0;i<7;++i){
          const float4 qa = *(const float4*)&qs[i*64 + wq*8];
          const float4 qb = *(const float4*)&qs[i*64 + wq*8 + 4];
          acc[i] += kf[0]*qa.x + kf[1]*qa.y + kf[2]*qa.z + kf[3]*qa.w
                  + kf[4]*qb.x + kf[5]*qb.y + kf[6]*qb.z + kf[7]*qb.w;
        }
      }
      float mx = -1e30f;
      #pragma unroll
      for (int i=0;i<7;++i){ acc[i] *= SCALE_; mx = fmaxf(mx, acc[i]); }
      float e[7]; float sum = 0.f;
      #pragma unroll
      for (int i=0;i<7;++i){ e[i] = __expf(acc[i]-mx); sum += e[i]; }
      const float inv = 1.f/sum;
      #pragma unroll
      for (int i=0;i<7;++i) at[i*TILE + t] = e[i]*inv + 1e-8f;
    }
    __syncthreads();
    {
      bf16x8 w0[4], w1[4]; float bc[4];
      #pragma unroll
      for (int cg=0; cg<4; ++cg){
        const int n = cg*16 + m;
        w0[cg] = frag8(Wv + n*64 + q4*8);
        w1[cg] = frag8(Wv + n*64 + 32 + q4*8);
        bc[cg] = bv[n];
      }
      #pragma unroll
      for (int rg=0; rg<2; ++rg){
        #pragma unroll
        for (int cg=0; cg<4; ++cg){
          f32x4 acc = {0.f,0.f,0.f,0.f};
          acc = __builtin_amdgcn_mfma_f32_16x16x32_bf16(af[rg][0], w0[cg], acc, 0,0,0);
          acc = __builtin_amdgcn_mfma_f32_16x16x32_bf16(af[rg][1], w1[cg], acc, 0,0,0);
          const int col = cg*16 + m;
          #pragma unroll
          for (int r=0;r<4;++r)
            tile[(wid*32 + rg*16 + q4*4 + r)*TPAD + col] = f2b(acc[r] + bc[cg]);
        }
      }
    }
    __syncthreads();
    #pragma unroll 4
    for (int j=0;j<TILE;++j){
      const unsigned vw = ((const unsigned*)&tile[j*TPAD])[lane>>1];
      const float vf = (lane&1) ? bhi(vw) : blo(vw);
      const float a0v = at[i0*TILE+j];
      n0 += a0v*vf; d0 += a0v;
      if (i1 < 7){ const float a1v = at[i1*TILE+j]; n1 += a1v*vf; d1 += a1v; }
    }
  }
  atomicAdd(&num[(b*7+i0)*64 + lane], n0);
  if (lane==0) atomicAdd(&den[b*7+i0], d0);
  if (i1 < 7){
    atomicAdd(&num[(b*7+i1)*64 + lane], n1);
    if (lane==0) atomicAdd(&den[b*7+i1], d1);
  }
}

// ---------------- FALLBACK per-iter: updates -> GRU -> residual MLP (+ next q) ----
__global__ __launch_bounds__(256) void k_gru_mlp(
  float* __restrict__ num, float* __restrict__ den, float* __restrict__ slots,
  const float* __restrict__ Wih, const float* __restrict__ Whh,
  const float* __restrict__ bih, const float* __restrict__ bhh,
  const float* __restrict__ mW1, const float* __restrict__ mb1,
  const float* __restrict__ mW2, const float* __restrict__ mb2,
  const float* __restrict__ g_ml, const float* __restrict__ b_ml,
  const float* __restrict__ Wq, const float* __restrict__ bq,
  const float* __restrict__ g_sl, const float* __restrict__ b_sl,
  const float* __restrict__ wkT, const float* __restrict__ bk,
  float* __restrict__ qout, float* __restrict__ qkb, float* __restrict__ qbb,
  float* __restrict__ outp, const int write_out, const int do_q)
{
  const int tid = blockIdx.x*256 + threadIdx.x;  // grid 56*256: 224 waves = 224 rows
  const int ri = tid>>6, lane = tid&63;
  const float dn = den[ri];
  const float u = (dn > 0.f) ? (num[tid] / dn) : 0.f;
  num[tid] = 0.f;
  if (lane == 0) den[ri] = 0.f;
  const float h = slots[tid];
  const float res = gru_mlp_row(u, h, lane, Wih, Whh, bih, bhh,
                                mW1, mb1, mW2, mb2, g_ml, b_ml);
  slots[tid] = res;
  if (write_out) outp[tid] = res;
  if (do_q)
    q_from_slots(res, ri, lane, Wq, bq, g_sl, b_sl, wkT, bk, qout, qkb, qbb, 0);
}

extern "C" void kernel_launch(void* const* d_in, const int* in_sizes, int n_in,
                              void* d_out, int out_size, void* d_ws, size_t ws_size,
                              hipStream_t stream)
{
  float* outp = (float*)d_out;
  static const int EXP[24] = {33554432,14336,64,64, 4096,64, 4096,64, 4096,64,
                              12288,12288,192,192, 8192,128, 8192,64,
                              64,64, 64,64, 64,64};
  if (n_in != 24){ k_marker<<<56,256,0,stream>>>(outp, out_size, 30.f); return; }
  for (int i=0;i<24;++i)
    if (in_sizes[i] != EXP[i]){ k_marker<<<56,256,0,stream>>>(outp, out_size, 40.f+(float)i); return; }
  if (out_size != 14336){ k_marker<<<56,256,0,stream>>>(outp, out_size, 33.f); return; }
  if (ws_size < 300000){ k_marker<<<56,256,0,stream>>>(outp, out_size, 35.f); return; }

  const float* inputs = (const float*)d_in[0];
  const float* noise  = (const float*)d_in[1];
  const float* mu     = (const float*)d_in[2];
  const float* sigma  = (const float*)d_in[3];
  const float* Wq  = (const float*)d_in[4];  const float* bq  = (const float*)d_in[5];
  const float* Wk  = (const float*)d_in[6];  const float* bk  = (const float*)d_in[7];
  const float* Wv  = (const float*)d_in[8];  const float* bv  = (const float*)d_in[9];
  const float* Wih = (const float*)d_in[10]; const float* Whh = (const float*)d_in[11];
  const float* bih = (const float*)d_in[12]; const float* bhh = (const float*)d_in[13];
  const float* mW1 = (const float*)d_in[14]; const float* mb1 = (const float*)d_in[15];
  const float* mW2 = (const float*)d_in[16]; const float* mb2 = (const float*)d_in[17];
  const float* g_in = (const float*)d_in[18]; const float* b_in = (const float*)d_in[19];
  const float* g_sl = (const float*)d_in[20]; const float* b_sl = (const float*)d_in[21];
  const float* g_ml = (const float*)d_in[22]; const float* b_ml = (const float*)d_in[23];

  char* ws = (char*)d_ws;
  float* slots = (float*)ws;                         // 14336 f
  float* qbuf  = (float*)(ws + 57344);               // 14336 f (plain q, fallback)
  float* qkb   = (float*)(ws + 114688);              // 14336 f (q @ Wk)
  float* num   = (float*)(ws + 172032);              // 14336 f (fallback)
  float* den   = (float*)(ws + 229376);              // 224 f (fallback)
  float* qbb   = (float*)(ws + 230272);              // 224 f (q . bk)
  float* wkT   = (float*)(ws + 231168);              // 4096 f (Wk^T), ends 247552
  int*   cnt2  = (int*)(ws + 247552);                // 64 ints: cntA(32) + cntB(32)
  float* pnum  = (float*)(ws + 247808);              // 1,835,008 f (7.34 MB partial num)
  float* pden  = (float*)(ws + 7587840);             // 28,672 f (partial den)
  u16* xln     = (u16*)(ws + 7702528);               // 33.5M bf16 (67.1 MB)
  const bool fast = (ws_size >= (size_t)7702528 + 67108864ull);

  if (fast){
    k_wkt<<<16,256,0,stream>>>(Wk, wkT);
    k_xln<<<2048,256,0,stream>>>(inputs, g_in, b_in, xln);
  }
  k_init_slots_q<<<56,256,0,stream>>>(mu, sigma, noise, slots,
                                      Wq, bq, g_sl, b_sl, wkT, bk,
                                      qbuf, qkb, qbb, num, den, cnt2, fast ? 1 : 0);
  if (fast){
    for (int it=0; it<3; ++it){
      int* cnt = (it == 1) ? (cnt2 + 32) : cnt2;   // iters 0,2 share A (finisher resets)
      k_attn7<<<4096,256,0,stream>>>(xln, qkb, qbb, pnum, pden, cnt, slots,
                                     Wv, bv, Wih, Whh, bih, bhh,
                                     mW1, mb1, mW2, mb2, g_ml, b_ml,
                                     Wq, bq, g_sl, b_sl, wkT, bk,
                                     qbuf, qkb, qbb, outp,
                                     it==2 ? 1 : 0, it<2 ? 1 : 0);
    }
  } else {
    for (int it=0; it<3; ++it){
      k_attn_fused<<<2048,256,0,stream>>>(inputs, Wk, bk, Wv, bv, g_in, b_in, qbuf, num, den);
      k_gru_mlp<<<56,256,0,stream>>>(num, den, slots, Wih, Whh, bih, bhh,
                                     mW1, mb1, mW2, mb2, g_ml, b_ml,
                                     Wq, bq, g_sl, b_sl, wkT, bk,
                                     qbuf, qkb, qbb, outp,
                                     it==2 ? 1 : 0, it<2 ? 1 : 0);
    }
  }
}

// Round 7
// 389.330 us; speedup vs baseline: 4.2276x; 4.2276x over previous
//
#include <hip/hip_runtime.h>
#include <hip/hip_bf16.h>

typedef unsigned short u16;
typedef __bf16 bf16x8 __attribute__((ext_vector_type(8)));
typedef float  f32x4  __attribute__((ext_vector_type(4)));

#define N_  16384
#define SCALE_ 0.125f
#define TILE 128
#define TPAD 66
#define AP6 136   // atb row stride (u16): 272B, 16B-aligned

__device__ __forceinline__ u16 f2b(float f){
  unsigned u = __float_as_uint(f);
  unsigned r = (u + 0x7fffu + ((u>>16)&1u)) >> 16;
  return (u16)r;
}
__device__ __forceinline__ float blo(unsigned u){ return __uint_as_float(u<<16); }
__device__ __forceinline__ float bhi(unsigned u){ return __uint_as_float(u & 0xffff0000u); }
__device__ __forceinline__ float b2f(u16 v){ return __uint_as_float(((unsigned)v)<<16); }
__device__ __forceinline__ void ld8(const float* __restrict__ p, float* f){
  const float4 a = ((const float4*)p)[0];
  const float4 b = ((const float4*)p)[1];
  f[0]=a.x; f[1]=a.y; f[2]=a.z; f[3]=a.w;
  f[4]=b.x; f[5]=b.y; f[6]=b.z; f[7]=b.w;
}
__device__ __forceinline__ bf16x8 frag8(const float* __restrict__ p){
  float f[8]; ld8(p, f);
  bf16x8 r;
  #pragma unroll
  for (int j=0;j<8;++j) r[j] = (__bf16)f[j];
  return r;
}

// ---------------- diagnostic marker (fp32 out) ----------------
__global__ __launch_bounds__(256) void k_marker(float* __restrict__ out, int n, float val){
  const int i = blockIdx.x*256 + threadIdx.x;
  if (i < n) out[i] = val;
}

// ---------------- shared helper: slots row -> q (and qk, q.bk) ----------------
__device__ __forceinline__ void q_from_slots(
  const float sv, const int ri, const int lane,
  const float* __restrict__ Wq, const float* __restrict__ bq,
  const float* __restrict__ g_sl, const float* __restrict__ b_sl,
  const float* __restrict__ wkT, const float* __restrict__ bk,
  float* __restrict__ qout, float* __restrict__ qkb, float* __restrict__ qbb,
  const int do_qk)
{
  float s = sv, ss = sv*sv;
  #pragma unroll
  for (int off=1; off<64; off<<=1){ s += __shfl_xor(s,off); ss += __shfl_xor(ss,off); }
  const float mean = s*(1.f/64.f);
  const float rstd = rsqrtf(ss*(1.f/64.f) - mean*mean + 1e-5f);
  const float sn = (sv-mean)*rstd*g_sl[lane] + b_sl[lane];
  float acc = 0.f;
  for (int d8=0; d8<8; ++d8){
    float wf[8]; ld8(Wq + lane*64 + d8*8, wf);
    #pragma unroll
    for (int j=0;j<8;++j) acc += __shfl(sn, d8*8+j) * wf[j];
  }
  const float qv = acc + bq[lane];
  qout[ri*64+lane] = qv;
  if (do_qk){
    float pb = qv * bk[lane];
    #pragma unroll
    for (int off=1; off<64; off<<=1) pb += __shfl_xor(pb, off);
    if (lane == 0) qbb[ri] = pb;
    float qkv = 0.f;
    for (int d8=0; d8<8; ++d8){
      float wf[8]; ld8(wkT + lane*64 + d8*8, wf);
      #pragma unroll
      for (int j=0;j<8;++j) qkv += __shfl(qv, d8*8+j) * wf[j];
    }
    qkb[ri*64+lane] = qkv;
  }
}

// ---------------- shared helper: one GRU+MLP row (full wave) ----------------
__device__ __forceinline__ float gru_mlp_row(
  const float u, const float h, const int lane,
  const float* __restrict__ Wih, const float* __restrict__ Whh,
  const float* __restrict__ bih, const float* __restrict__ bhh,
  const float* __restrict__ mW1, const float* __restrict__ mb1,
  const float* __restrict__ mW2, const float* __restrict__ mb2,
  const float* __restrict__ g_ml, const float* __restrict__ b_ml)
{
  float air=0,aiz=0,ain=0,ahr=0,ahz=0,ahn=0;
  for (int d8=0; d8<8; ++d8){
    float fir[8],fiz[8],fin[8],fhr[8],fhz[8],fhn[8];
    ld8(Wih + (      lane)*64 + d8*8, fir);
    ld8(Wih + ( 64 + lane)*64 + d8*8, fiz);
    ld8(Wih + (128 + lane)*64 + d8*8, fin);
    ld8(Whh + (      lane)*64 + d8*8, fhr);
    ld8(Whh + ( 64 + lane)*64 + d8*8, fhz);
    ld8(Whh + (128 + lane)*64 + d8*8, fhn);
    #pragma unroll
    for (int j=0;j<8;++j){
      const float ud = __shfl(u, d8*8+j);
      const float hd = __shfl(h, d8*8+j);
      air += ud*fir[j]; aiz += ud*fiz[j]; ain += ud*fin[j];
      ahr += hd*fhr[j]; ahz += hd*fhz[j]; ahn += hd*fhn[j];
    }
  }
  air += bih[lane]; aiz += bih[64+lane]; ain += bih[128+lane];
  ahr += bhh[lane]; ahz += bhh[64+lane]; ahn += bhh[128+lane];
  const float r = 1.f/(1.f + __expf(-(air+ahr)));
  const float z = 1.f/(1.f + __expf(-(aiz+ahz)));
  const float n = tanhf(ain + r*ahn);
  const float sv = (1.f-z)*n + z*h;
  float s=sv, ss=sv*sv;
  #pragma unroll
  for (int off=1; off<64; off<<=1){ s += __shfl_xor(s,off); ss += __shfl_xor(ss,off); }
  const float mean = s*(1.f/64.f);
  const float rstd = rsqrtf(ss*(1.f/64.f) - mean*mean + 1e-5f);
  const float m = (sv-mean)*rstd*g_ml[lane] + b_ml[lane];
  float h1a=0.f, h1b=0.f;
  for (int d8=0; d8<8; ++d8){
    float f1[8], f2[8];
    ld8(mW1 + (     lane)*64 + d8*8, f1);
    ld8(mW1 + (64 + lane)*64 + d8*8, f2);
    #pragma unroll
    for (int j=0;j<8;++j){
      const float md = __shfl(m, d8*8+j);
      h1a += md*f1[j]; h1b += md*f2[j];
    }
  }
  h1a = fmaxf(h1a + mb1[lane], 0.f);
  h1b = fmaxf(h1b + mb1[64+lane], 0.f);
  float o = 0.f;
  for (int h8=0; h8<8; ++h8){
    float fa[8], fb[8];
    ld8(mW2 + lane*128 + h8*8, fa);
    ld8(mW2 + lane*128 + 64 + h8*8, fb);
    #pragma unroll
    for (int j=0;j<8;++j){
      o += __shfl(h1a, h8*8+j)*fa[j] + __shfl(h1b, h8*8+j)*fb[j];
    }
  }
  o += mb2[lane];
  return sv + o;
}

// ---------------- slots init (+ first q, + zero num/den) ----------------
__global__ __launch_bounds__(256) void k_init_slots_q(
  const float* __restrict__ mu, const float* __restrict__ sigma,
  const float* __restrict__ noise, float* __restrict__ slots,
  const float* __restrict__ Wq, const float* __restrict__ bq,
  const float* __restrict__ g_sl, const float* __restrict__ b_sl,
  const float* __restrict__ wkT, const float* __restrict__ bk,
  float* __restrict__ qout, float* __restrict__ qkb, float* __restrict__ qbb,
  float* __restrict__ num, float* __restrict__ den, const int do_qk)
{
  const int tid = blockIdx.x*256 + threadIdx.x;   // grid 56*256 = 14336 exact
  const int ri = tid>>6, lane = tid&63;
  const float sv = mu[lane] + sigma[lane] * noise[tid];
  slots[tid] = sv;
  num[tid] = 0.f;
  if (tid < 224) den[tid] = 0.f;
  q_from_slots(sv, ri, lane, Wq, bq, g_sl, b_sl, wkT, bk, qout, qkb, qbb, do_qk);
}

// ---------------- Wk transpose: wkT[e][d] = Wk[d][e] (once) ----------------
__global__ __launch_bounds__(256) void k_wkt(const float* __restrict__ Wk, float* __restrict__ wkT){
  const int i = blockIdx.x*256 + threadIdx.x;     // grid 16*256 = 4096 exact
  const int e = i>>6, d = i&63;
  wkT[i] = Wk[d*64 + e];
}

// ================= FAST PATH: MFMA streaming attention v8 =================
// grid = 32 b x 128 ch (128 keys/block). first=1: read x fp32, LN in-register
// (k_kv-verified 16-rows-per-wave pattern), stage bf16 into swizzled LDS AND
// write x̂ back to global (coalesced via inverse-swizzle LDS read) for iters
// 1-2. first=0: stage from the bf16 x̂ buffer. Phases A/B and partial stores
// identical to verified round-4 attn6. No global atomics, no fences.
// NOTE: xg/xln intentionally NOT __restrict__ — they alias the same workspace
// buffer (only one is dereferenced per dispatch, selected by `first`).
__global__ __launch_bounds__(256) void k_attn8(
  const float* __restrict__ x, u16* xg, const u16* xln,
  const float* __restrict__ g_in, const float* __restrict__ b_in,
  const float* __restrict__ qkb, const float* __restrict__ qbb,
  float* __restrict__ pnum, float* __restrict__ pden, const int first)
{
  __shared__ __align__(16) u16   xs[128*64];      // 16 KB swizzled x̂ tile
  __shared__ __align__(16) u16   atb[7*AP6];      // bf16 attn weights
  __shared__ __align__(16) float dlds[128*9];     // dots (stride-9 pad)
  __shared__ float qbs[7];
  __shared__ float den_s[7];
  const int t = threadIdx.x;
  const int b = blockIdx.x >> 7, ch = blockIdx.x & 127;
  const int wid = t>>6, lane = t&63;
  const int m15 = lane&15, g4 = lane>>4;

  if (t < 7){ qbs[t] = qbb[b*7+t]; den_s[t] = 0.f; }
  // qk B-frags (slot n = m15, dims f*32 + g4*8 + j), slots 7..15 zero
  bf16x8 qf[2];
  #pragma unroll
  for (int f=0; f<2; ++f){
    float tmp[8];
    if (m15 < 7){ ld8(qkb + b*448 + m15*64 + f*32 + g4*8, tmp); }
    else {
      #pragma unroll
      for (int j=0;j<8;++j) tmp[j]=0.f;
    }
    #pragma unroll
    for (int j=0;j<8;++j) qf[f][j] = (__bf16)tmp[j];
  }

  if (first){
    // ---- iter0: fp32 read + in-register LayerNorm (k_kv pattern) ----
    float gf[16], bfv[16];
    ld8(g_in + g4*8, gf);  ld8(g_in + 32 + g4*8, gf+8);
    ld8(b_in + g4*8, bfv); ld8(b_in + 32 + g4*8, bfv+8);
    #pragma unroll
    for (int p=0;p<2;++p){
      const int rl = p*64 + wid*16 + m15;       // local row 0..127, each once
      const long grow = (long)b*N_ + ch*128 + rl;
      const float* xr = x + grow*64;
      float xf[16];
      ld8(xr + g4*8, xf); ld8(xr + 32 + g4*8, xf+8);
      float s=0.f, ss=0.f;
      #pragma unroll
      for (int i=0;i<16;++i){ s += xf[i]; ss += xf[i]*xf[i]; }
      s  += __shfl_xor(s,16);  s  += __shfl_xor(s,32);
      ss += __shfl_xor(ss,16); ss += __shfl_xor(ss,32);
      const float mean = s*(1.f/64.f);
      const float rstd = rsqrtf(ss*(1.f/64.f) - mean*mean + 1e-5f);
      unsigned pw[8];
      #pragma unroll
      for (int j=0;j<8;++j){
        const u16 lo = f2b((xf[2*j]  -mean)*rstd*gf[2*j]   + bfv[2*j]);
        const u16 hi = f2b((xf[2*j+1]-mean)*rstd*gf[2*j+1] + bfv[2*j+1]);
        pw[j] = (unsigned)lo | ((unsigned)hi<<16);
      }
      // chunk c0 = g4 (dims g4*8..+7), chunk c1 = 4+g4 (dims 32+g4*8..+7)
      *(uint4*)&xs[rl*64 + (((g4  ) ^ (rl&7))<<3)] = make_uint4(pw[0],pw[1],pw[2],pw[3]);
      *(uint4*)&xs[rl*64 + (((4+g4) ^ (rl&7))<<3)] = make_uint4(pw[4],pw[5],pw[6],pw[7]);
    }
  } else {
    // ---- iters 1,2: stage bf16 x̂ tile: 4 x b128 per thread ----
    const u16* gbase = xln + ((long)b*N_ + ch*128)*64;
    uint4 st[4];
    #pragma unroll
    for (int p=0;p<4;++p) st[p] = *(const uint4*)(gbase + p*2048 + t*8);
    #pragma unroll
    for (int p=0;p<4;++p)
      *(uint4*)&xs[(p*32 + (t>>3))*64 + (((t&7) ^ ((t>>3)&7))<<3)] = st[p];
  }
  __syncthreads();

  if (first){
    // coalesced global writeback of x̂ for iters 1-2 (inverse-swizzle read)
    u16* gb = xg + ((long)b*N_ + ch*128)*64;
    #pragma unroll
    for (int p=0;p<4;++p){
      const int r = p*32 + (t>>3), c = t&7;
      const uint4 v = *(const uint4*)&xs[r*64 + ((c ^ (r&7))<<3)];
      *(uint4*)(gb + r*64 + c*8) = v;
    }
  }

  // ---- phase A: dots[key][slot] via MFMA ----
  #pragma unroll
  for (int mt=0; mt<2; ++mt){
    const int kr = (wid<<5) + (mt<<4) + m15;      // A: m=key
    f32x4 dacc = {0.f,0.f,0.f,0.f};
    #pragma unroll
    for (int f=0; f<2; ++f){
      const int c = (f<<2) + g4;                  // 16B chunk = dim/8
      const uint4 aw = *(const uint4*)&xs[kr*64 + ((c ^ (kr&7))<<3)];
      dacc = __builtin_amdgcn_mfma_f32_16x16x32_bf16(
               __builtin_bit_cast(bf16x8, aw), qf[f], dacc, 0,0,0);
    }
    if (m15 < 7){                                 // C: col=slot, row=key in 16
      const int krow = (wid<<5) + (mt<<4) + (g4<<2);
      #pragma unroll
      for (int r=0;r<4;++r) dlds[(krow+r)*9 + m15] = dacc[r];
    }
  }
  __syncthreads();

  // ---- per-key softmax over 7 slots (threads 0..127) ----
  if (t < 128){
    float acc[7];
    #pragma unroll
    for (int i=0;i<7;++i) acc[i] = (dlds[t*9+i] + qbs[i]) * SCALE_;
    float mx = -1e30f;
    #pragma unroll
    for (int i=0;i<7;++i) mx = fmaxf(mx, acc[i]);
    float e[7]; float sum = 0.f;
    #pragma unroll
    for (int i=0;i<7;++i){ e[i] = __expf(acc[i]-mx); sum += e[i]; }
    const float inv = 1.f/sum;
    float dsum[7];
    #pragma unroll
    for (int i=0;i<7;++i){
      const u16 rb = f2b(e[i]*inv + 1e-8f);
      atb[i*AP6 + t] = rb;
      dsum[i] = b2f(rb);            // den from the SAME rounded weights as num
    }
    #pragma unroll
    for (int i=0;i<7;++i){
      #pragma unroll
      for (int off=1; off<64; off<<=1) dsum[i] += __shfl_xor(dsum[i], off);
    }
    if (lane == 0){
      #pragma unroll
      for (int i=0;i<7;++i) atomicAdd(&den_s[i], dsum[i]);   // LDS atomic only
    }
  }
  __syncthreads();

  // ---- phase B: num^T[dim][slot] += x̂^T[dim][key] @ attn^T[key][slot] ----
  const int dim2 = ((wid<<4) + m15) << 1;   // byte col of this lane's A-dim
  f32x4 accv = {0.f,0.f,0.f,0.f};
  #pragma unroll
  for (int ks=0; ks<4; ++ks){
    const int kbase = (ks<<5) + (g4<<3);    // key base, multiple of 8
    const unsigned a0 = xs[(kbase+0)*64 + ((dim2 ^ (0<<4))>>1)];
    const unsigned a1 = xs[(kbase+1)*64 + ((dim2 ^ (1<<4))>>1)];
    const unsigned a2 = xs[(kbase+2)*64 + ((dim2 ^ (2<<4))>>1)];
    const unsigned a3 = xs[(kbase+3)*64 + ((dim2 ^ (3<<4))>>1)];
    const unsigned a4 = xs[(kbase+4)*64 + ((dim2 ^ (4<<4))>>1)];
    const unsigned a5 = xs[(kbase+5)*64 + ((dim2 ^ (5<<4))>>1)];
    const unsigned a6 = xs[(kbase+6)*64 + ((dim2 ^ (6<<4))>>1)];
    const unsigned a7 = xs[(kbase+7)*64 + ((dim2 ^ (7<<4))>>1)];
    const uint4 aw = make_uint4(a0|(a1<<16), a2|(a3<<16), a4|(a5<<16), a6|(a7<<16));
    const bf16x8 af = __builtin_bit_cast(bf16x8, aw);
    uint4 bw = make_uint4(0u,0u,0u,0u);
    if (m15 < 7) bw = *(const uint4*)&atb[m15*AP6 + kbase];
    const bf16x8 bfv = __builtin_bit_cast(bf16x8, bw);
    accv = __builtin_amdgcn_mfma_f32_16x16x32_bf16(af, bfv, accv, 0,0,0);
  }

  // ---- plain-store partials (no atomics, no fences) ----
  if (m15 < 7){
    float* np = &pnum[(((long)b*7 + m15)*128 + ch)*64 + (wid<<4) + (g4<<2)];
    #pragma unroll
    for (int r=0;r<4;++r) np[r] = accv[r];
  }
  if (t < 7) pden[(b*7+t)*128 + ch] = den_s[t];
}

// ================= FALLBACK: fused attention (verified) =================
__global__ __launch_bounds__(256) void k_attn_fused(
  const float* __restrict__ x,
  const float* __restrict__ Wk, const float* __restrict__ bk,
  const float* __restrict__ Wv, const float* __restrict__ bv,
  const float* __restrict__ g_in, const float* __restrict__ b_in,
  const float* __restrict__ qbuf, float* __restrict__ num, float* __restrict__ den)
{
  __shared__ __align__(16) u16   tile[TILE*TPAD];
  __shared__ __align__(16) float qs[7*64];
  __shared__ __align__(16) float at[7*TILE];
  const int t = threadIdx.x;
  const int b = blockIdx.x >> 6, ch = blockIdx.x & 63;
  for (int i=t; i<448; i+=256) qs[i] = qbuf[b*448 + i];
  const int wid = t>>6, lane = t&63;
  const int m = lane & 15, q4 = lane >> 4;
  float gf[16], bfv[16];
  ld8(g_in + q4*8, gf);  ld8(g_in + 32 + q4*8, gf+8);
  ld8(b_in + q4*8, bfv); ld8(b_in + 32 + q4*8, bfv+8);
  const int i0 = wid*2, i1 = wid*2+1;
  float n0=0.f, n1=0.f, d0=0.f, d1=0.f;

  for (int tl=0; tl<2; ++tl){
    const long j0 = (long)ch*256 + tl*TILE;
    const long rowbase = (long)b*N_ + j0 + (long)wid*32;
    __syncthreads();
    bf16x8 af[2][2];
    #pragma unroll
    for (int rg=0; rg<2; ++rg){
      const float* xr = x + (rowbase + rg*16 + m)*64;
      float xf[16];
      ld8(xr + q4*8, xf); ld8(xr + 32 + q4*8, xf+8);
      float s=0.f, ss=0.f;
      #pragma unroll
      for (int i=0;i<16;++i){ s += xf[i]; ss += xf[i]*xf[i]; }
      s  += __shfl_xor(s,16);  s  += __shfl_xor(s,32);
      ss += __shfl_xor(ss,16); ss += __shfl_xor(ss,32);
      const float mean = s*(1.f/64.f);
      const float rstd = rsqrtf(ss*(1.f/64.f) - mean*mean + 1e-5f);
      #pragma unroll
      for (int j=0;j<8;++j){
        af[rg][0][j] = (__bf16)((xf[j]  -mean)*rstd*gf[j]   + bfv[j]);
        af[rg][1][j] = (__bf16)((xf[8+j]-mean)*rstd*gf[8+j] + bfv[8+j]);
      }
    }
    {
      bf16x8 w0[4], w1[4]; float bc[4];
      #pragma unroll
      for (int cg=0; cg<4; ++cg){
        const int n = cg*16 + m;
        w0[cg] = frag8(Wk + n*64 + q4*8);
        w1[cg] = frag8(Wk + n*64 + 32 + q4*8);
        bc[cg] = bk[n];
      }
      #pragma unroll
      for (int rg=0; rg<2; ++rg){
        #pragma unroll
        for (int cg=0; cg<4; ++cg){
          f32x4 acc = {0.f,0.f,0.f,0.f};
          acc = __builtin_amdgcn_mfma_f32_16x16x32_bf16(af[rg][0], w0[cg], acc, 0,0,0);
          acc = __builtin_amdgcn_mfma_f32_16x16x32_bf16(af[rg][1], w1[cg], acc, 0,0,0);
          const int col = cg*16 + m;
          #pragma unroll
          for (int r=0;r<4;++r)
            tile[(wid*32 + rg*16 + q4*4 + r)*TPAD + col] = f2b(acc[r] + bc[cg]);
        }
      }
    }
    __syncthreads();
    if (t < TILE){
      float acc[7];
      #pragma unroll
      for (int i=0;i<7;++i) acc[i]=0.f;
      const unsigned* krow = (const unsigned*)&tile[t*TPAD];
      for (int wq=0; wq<8; ++wq){
        const unsigned k0 = krow[wq*4+0], k1 = krow[wq*4+1], k2 = krow[wq*4+2], k3 = krow[wq*4+3];
        float kf[8];
        kf[0]=blo(k0); kf[1]=bhi(k0); kf[2]=blo(k1); kf[3]=bhi(k1);
        kf[4]=blo(k2); kf[5]=bhi(k2); kf[6]=blo(k3); kf[7]=bhi(k3);
        #pragma unroll
        for (int i=0;i<7;++i){
          const float4 qa = *(const float4*)&qs[i*64 + wq*8];
          const float4 qb = *(const float4*)&qs[i*64 + wq*8 + 4];
          acc[i] += kf[0]*qa.x + kf[1]*qa.y + kf[2]*qa.z + kf[3]*qa.w
                  + kf[4]*qb.x + kf[5]*qb.y + kf[6]*qb.z + kf[7]*qb.w;
        }
      }
      float mx = -1e30f;
      #pragma unroll
      for (int i=0;i<7;++i){ acc[i] *= SCALE_; mx = fmaxf(mx, acc[i]); }
      float e[7]; float sum = 0.f;
      #pragma unroll
      for (int i=0;i<7;++i){ e[i] = __expf(acc[i]-mx); sum += e[i]; }
      const float inv = 1.f/sum;
      #pragma unroll
      for (int i=0;i<7;++i) at[i*TILE + t] = e[i]*inv + 1e-8f;
    }
    __syncthreads();
    {
      bf16x8 w0[4], w1[4]; float bc[4];
      #pragma unroll
      for (int cg=0; cg<4; ++cg){
        const int n = cg*16 + m;
        w0[cg] = frag8(Wv + n*64 + q4*8);
        w1[cg] = frag8(Wv + n*64 + 32 + q4*8);
        bc[cg] = bv[n];
      }
      #pragma unroll
      for (int rg=0; rg<2; ++rg){
        #pragma unroll
        for (int cg=0; cg<4; ++cg){
          f32x4 acc = {0.f,0.f,0.f,0.f};
          acc = __builtin_amdgcn_mfma_f32_16x16x32_bf16(af[rg][0], w0[cg], acc, 0,0,0);
          acc = __builtin_amdgcn_mfma_f32_16x16x32_bf16(af[rg][1], w1[cg], acc, 0,0,0);
          const int col = cg*16 + m;
          #pragma unroll
          for (int r=0;r<4;++r)
            tile[(wid*32 + rg*16 + q4*4 + r)*TPAD + col] = f2b(acc[r] + bc[cg]);
        }
      }
    }
    __syncthreads();
    #pragma unroll 4
    for (int j=0;j<TILE;++j){
      const unsigned vw = ((const unsigned*)&tile[j*TPAD])[lane>>1];
      const float vf = (lane&1) ? bhi(vw) : blo(vw);
      const float a0v = at[i0*TILE+j];
      n0 += a0v*vf; d0 += a0v;
      if (i1 < 7){ const float a1v = at[i1*TILE+j]; n1 += a1v*vf; d1 += a1v; }
    }
  }
  atomicAdd(&num[(b*7+i0)*64 + lane], n0);
  if (lane==0) atomicAdd(&den[b*7+i0], d0);
  if (i1 < 7){
    atomicAdd(&num[(b*7+i1)*64 + lane], n1);
    if (lane==0) atomicAdd(&den[b*7+i1], d1);
  }
}

// ---------------- per-iter: updates -> GRU -> residual MLP (+ next q) ----------------
__global__ __launch_bounds__(256) void k_gru_mlp(
  float* __restrict__ num, float* __restrict__ den,
  const float* __restrict__ pnum, const float* __restrict__ pden,
  float* __restrict__ slots,
  const float* __restrict__ Wv, const float* __restrict__ bv,
  const float* __restrict__ Wih, const float* __restrict__ Whh,
  const float* __restrict__ bih, const float* __restrict__ bhh,
  const float* __restrict__ mW1, const float* __restrict__ mb1,
  const float* __restrict__ mW2, const float* __restrict__ mb2,
  const float* __restrict__ g_ml, const float* __restrict__ b_ml,
  const float* __restrict__ Wq, const float* __restrict__ bq,
  const float* __restrict__ g_sl, const float* __restrict__ b_sl,
  const float* __restrict__ wkT, const float* __restrict__ bk,
  float* __restrict__ qout, float* __restrict__ qkb, float* __restrict__ qbb,
  float* __restrict__ outp,
  const int write_out, const int fastmode, const int do_q, const int do_qk)
{
  const int tid = blockIdx.x*256 + threadIdx.x;  // grid 56*256: 224 waves = 224 rows
  const int ri = tid>>6, lane = tid&63;
  float a;
  if (fastmode){
    // reduce the 128 per-chunk partials (plain loads, no atomics upstream)
    float asum = 0.f;
    const float* pn = pnum + (long)ri*8192 + lane;   // [(ri*128 + c)*64 + lane]
    #pragma unroll 8
    for (int c=0;c<128;++c) asum += pn[c*64];
    float v = pden[ri*128 + lane] + pden[ri*128 + 64 + lane];
    #pragma unroll
    for (int off=1; off<64; off<<=1) v += __shfl_xor(v, off);
    const float dn = v;
    a = (dn > 0.f) ? (asum / dn) : 0.f;
  } else {
    const float dn = den[ri];
    a = (dn > 0.f) ? (num[tid] / dn) : 0.f;
    num[tid] = 0.f;                 // re-zero for next iter
    if (lane == 0) den[ri] = 0.f;
  }
  float u;
  if (fastmode){
    float acc = 0.f;
    for (int e8=0; e8<8; ++e8){
      float f[8]; ld8(Wv + lane*64 + e8*8, f);
      #pragma unroll
      for (int j=0;j<8;++j) acc += __shfl(a, e8*8+j) * f[j];
    }
    u = acc + bv[lane];
  } else {
    u = a;
  }
  const float h = slots[tid];
  const float res = gru_mlp_row(u, h, lane, Wih, Whh, bih, bhh,
                                mW1, mb1, mW2, mb2, g_ml, b_ml);
  slots[tid] = res;
  if (write_out) outp[tid] = res;
  if (do_q)
    q_from_slots(res, ri, lane, Wq, bq, g_sl, b_sl, wkT, bk, qout, qkb, qbb, do_qk);
}

extern "C" void kernel_launch(void* const* d_in, const int* in_sizes, int n_in,
                              void* d_out, int out_size, void* d_ws, size_t ws_size,
                              hipStream_t stream)
{
  float* outp = (float*)d_out;
  static const int EXP[24] = {33554432,14336,64,64, 4096,64, 4096,64, 4096,64,
                              12288,12288,192,192, 8192,128, 8192,64,
                              64,64, 64,64, 64,64};
  if (n_in != 24){ k_marker<<<56,256,0,stream>>>(outp, out_size, 30.f); return; }
  for (int i=0;i<24;++i)
    if (in_sizes[i] != EXP[i]){ k_marker<<<56,256,0,stream>>>(outp, out_size, 40.f+(float)i); return; }
  if (out_size != 14336){ k_marker<<<56,256,0,stream>>>(outp, out_size, 33.f); return; }
  if (ws_size < 300000){ k_marker<<<56,256,0,stream>>>(outp, out_size, 35.f); return; }

  const float* inputs = (const float*)d_in[0];
  const float* noise  = (const float*)d_in[1];
  const float* mu     = (const float*)d_in[2];
  const float* sigma  = (const float*)d_in[3];
  const float* Wq  = (const float*)d_in[4];  const float* bq  = (const float*)d_in[5];
  const float* Wk  = (const float*)d_in[6];  const float* bk  = (const float*)d_in[7];
  const float* Wv  = (const float*)d_in[8];  const float* bv  = (const float*)d_in[9];
  const float* Wih = (const float*)d_in[10]; const float* Whh = (const float*)d_in[11];
  const float* bih = (const float*)d_in[12]; const float* bhh = (const float*)d_in[13];
  const float* mW1 = (const float*)d_in[14]; const float* mb1 = (const float*)d_in[15];
  const float* mW2 = (const float*)d_in[16]; const float* mb2 = (const float*)d_in[17];
  const float* g_in = (const float*)d_in[18]; const float* b_in = (const float*)d_in[19];
  const float* g_sl = (const float*)d_in[20]; const float* b_sl = (const float*)d_in[21];
  const float* g_ml = (const float*)d_in[22]; const float* b_ml = (const float*)d_in[23];

  char* ws = (char*)d_ws;
  float* slots = (float*)ws;                         // 14336 f
  float* qbuf  = (float*)(ws + 57344);               // 14336 f (plain q, fallback)
  float* qkb   = (float*)(ws + 114688);              // 14336 f (q @ Wk)
  float* num   = (float*)(ws + 172032);              // 14336 f (fallback)
  float* den   = (float*)(ws + 229376);              // 224 f (fallback)
  float* qbb   = (float*)(ws + 230272);              // 224 f (q . bk)
  float* wkT   = (float*)(ws + 231168);              // 4096 f (Wk^T)
  float* pnum  = (float*)(ws + 247808);              // 1,835,008 f (7.34 MB partial num)
  float* pden  = (float*)(ws + 7587840);             // 28,672 f (partial den)
  u16* xln     = (u16*)(ws + 7702528);               // 33.5M bf16 (67.1 MB)
  const bool fast = (ws_size >= (size_t)7702528 + 67108864ull);

  if (fast)
    k_wkt<<<16,256,0,stream>>>(Wk, wkT);
  k_init_slots_q<<<56,256,0,stream>>>(mu, sigma, noise, slots,
                                      Wq, bq, g_sl, b_sl, wkT, bk,
                                      qbuf, qkb, qbb, num, den, fast ? 1 : 0);
  if (fast){
    for (int it=0; it<3; ++it){
      k_attn8<<<4096,256,0,stream>>>(inputs, xln, xln, g_in, b_in,
                                     qkb, qbb, pnum, pden, it==0 ? 1 : 0);
      k_gru_mlp<<<56,256,0,stream>>>(num, den, pnum, pden, slots, Wv, bv,
                                     Wih, Whh, bih, bhh,
                                     mW1, mb1, mW2, mb2, g_ml, b_ml,
                                     Wq, bq, g_sl, b_sl, wkT, bk,
                                     qbuf, qkb, qbb, outp,
                                     it==2 ? 1 : 0, 1,
                                     it<2 ? 1 : 0, it<2 ? 1 : 0);
    }
  } else {
    for (int it=0; it<3; ++it){
      k_attn_fused<<<2048,256,0,stream>>>(inputs, Wk, bk, Wv, bv, g_in, b_in, qbuf, num, den);
      k_gru_mlp<<<56,256,0,stream>>>(num, den, pnum, pden, slots, Wv, bv,
                                     Wih, Whh, bih, bhh,
                                     mW1, mb1, mW2, mb2, g_ml, b_ml,
                                     Wq, bq, g_sl, b_sl, wkT, bk,
                                     qbuf, qkb, qbb, outp,
                                     it==2 ? 1 : 0, 0,
                                     it<2 ? 1 : 0, 0);
    }
  }
}

// Round 8
// 382.747 us; speedup vs baseline: 4.3004x; 1.0172x over previous
//
#include <hip/hip_runtime.h>
#include <hip/hip_bf16.h>

typedef unsigned short u16;
typedef __bf16 bf16x8 __attribute__((ext_vector_type(8)));
typedef float  f32x4  __attribute__((ext_vector_type(4)));

#define N_  16384
#define SCALE_ 0.125f
#define TILE 128
#define TPAD 66
#define AP6 136   // atb row stride (u16): 272B, 16B-aligned

__device__ __forceinline__ u16 f2b(float f){
  unsigned u = __float_as_uint(f);
  unsigned r = (u + 0x7fffu + ((u>>16)&1u)) >> 16;
  return (u16)r;
}
__device__ __forceinline__ float blo(unsigned u){ return __uint_as_float(u<<16); }
__device__ __forceinline__ float bhi(unsigned u){ return __uint_as_float(u & 0xffff0000u); }
__device__ __forceinline__ float b2f(u16 v){ return __uint_as_float(((unsigned)v)<<16); }
__device__ __forceinline__ void ld8(const float* __restrict__ p, float* f){
  const float4 a = ((const float4*)p)[0];
  const float4 b = ((const float4*)p)[1];
  f[0]=a.x; f[1]=a.y; f[2]=a.z; f[3]=a.w;
  f[4]=b.x; f[5]=b.y; f[6]=b.z; f[7]=b.w;
}
__device__ __forceinline__ bf16x8 frag8(const float* __restrict__ p){
  float f[8]; ld8(p, f);
  bf16x8 r;
  #pragma unroll
  for (int j=0;j<8;++j) r[j] = (__bf16)f[j];
  return r;
}

// ---------------- diagnostic marker (fp32 out) ----------------
__global__ __launch_bounds__(256) void k_marker(float* __restrict__ out, int n, float val){
  const int i = blockIdx.x*256 + threadIdx.x;
  if (i < n) out[i] = val;
}

// ---------------- shared helper: slots row -> q (and qk, q.bk) ----------------
__device__ __forceinline__ void q_from_slots(
  const float sv, const int ri, const int lane,
  const float* __restrict__ Wq, const float* __restrict__ bq,
  const float* __restrict__ g_sl, const float* __restrict__ b_sl,
  const float* __restrict__ wkT, const float* __restrict__ bk,
  float* __restrict__ qout, float* __restrict__ qkb, float* __restrict__ qbb,
  const int do_qk)
{
  float s = sv, ss = sv*sv;
  #pragma unroll
  for (int off=1; off<64; off<<=1){ s += __shfl_xor(s,off); ss += __shfl_xor(ss,off); }
  const float mean = s*(1.f/64.f);
  const float rstd = rsqrtf(ss*(1.f/64.f) - mean*mean + 1e-5f);
  const float sn = (sv-mean)*rstd*g_sl[lane] + b_sl[lane];
  float acc = 0.f;
  for (int d8=0; d8<8; ++d8){
    float wf[8]; ld8(Wq + lane*64 + d8*8, wf);
    #pragma unroll
    for (int j=0;j<8;++j) acc += __shfl(sn, d8*8+j) * wf[j];
  }
  const float qv = acc + bq[lane];
  qout[ri*64+lane] = qv;
  if (do_qk){
    float pb = qv * bk[lane];
    #pragma unroll
    for (int off=1; off<64; off<<=1) pb += __shfl_xor(pb, off);
    if (lane == 0) qbb[ri] = pb;
    float qkv = 0.f;
    for (int d8=0; d8<8; ++d8){
      float wf[8]; ld8(wkT + lane*64 + d8*8, wf);
      #pragma unroll
      for (int j=0;j<8;++j) qkv += __shfl(qv, d8*8+j) * wf[j];
    }
    qkb[ri*64+lane] = qkv;
  }
}

// ---------------- shared helper: one GRU+MLP row (full wave) ----------------
__device__ __forceinline__ float gru_mlp_row(
  const float u, const float h, const int lane,
  const float* __restrict__ Wih, const float* __restrict__ Whh,
  const float* __restrict__ bih, const float* __restrict__ bhh,
  const float* __restrict__ mW1, const float* __restrict__ mb1,
  const float* __restrict__ mW2, const float* __restrict__ mb2,
  const float* __restrict__ g_ml, const float* __restrict__ b_ml)
{
  float air=0,aiz=0,ain=0,ahr=0,ahz=0,ahn=0;
  for (int d8=0; d8<8; ++d8){
    float fir[8],fiz[8],fin[8],fhr[8],fhz[8],fhn[8];
    ld8(Wih + (      lane)*64 + d8*8, fir);
    ld8(Wih + ( 64 + lane)*64 + d8*8, fiz);
    ld8(Wih + (128 + lane)*64 + d8*8, fin);
    ld8(Whh + (      lane)*64 + d8*8, fhr);
    ld8(Whh + ( 64 + lane)*64 + d8*8, fhz);
    ld8(Whh + (128 + lane)*64 + d8*8, fhn);
    #pragma unroll
    for (int j=0;j<8;++j){
      const float ud = __shfl(u, d8*8+j);
      const float hd = __shfl(h, d8*8+j);
      air += ud*fir[j]; aiz += ud*fiz[j]; ain += ud*fin[j];
      ahr += hd*fhr[j]; ahz += hd*fhz[j]; ahn += hd*fhn[j];
    }
  }
  air += bih[lane]; aiz += bih[64+lane]; ain += bih[128+lane];
  ahr += bhh[lane]; ahz += bhh[64+lane]; ahn += bhh[128+lane];
  const float r = 1.f/(1.f + __expf(-(air+ahr)));
  const float z = 1.f/(1.f + __expf(-(aiz+ahz)));
  const float n = tanhf(ain + r*ahn);
  const float sv = (1.f-z)*n + z*h;
  float s=sv, ss=sv*sv;
  #pragma unroll
  for (int off=1; off<64; off<<=1){ s += __shfl_xor(s,off); ss += __shfl_xor(ss,off); }
  const float mean = s*(1.f/64.f);
  const float rstd = rsqrtf(ss*(1.f/64.f) - mean*mean + 1e-5f);
  const float m = (sv-mean)*rstd*g_ml[lane] + b_ml[lane];
  float h1a=0.f, h1b=0.f;
  for (int d8=0; d8<8; ++d8){
    float f1[8], f2[8];
    ld8(mW1 + (     lane)*64 + d8*8, f1);
    ld8(mW1 + (64 + lane)*64 + d8*8, f2);
    #pragma unroll
    for (int j=0;j<8;++j){
      const float md = __shfl(m, d8*8+j);
      h1a += md*f1[j]; h1b += md*f2[j];
    }
  }
  h1a = fmaxf(h1a + mb1[lane], 0.f);
  h1b = fmaxf(h1b + mb1[64+lane], 0.f);
  float o = 0.f;
  for (int h8=0; h8<8; ++h8){
    float fa[8], fb[8];
    ld8(mW2 + lane*128 + h8*8, fa);
    ld8(mW2 + lane*128 + 64 + h8*8, fb);
    #pragma unroll
    for (int j=0;j<8;++j){
      o += __shfl(h1a, h8*8+j)*fa[j] + __shfl(h1b, h8*8+j)*fb[j];
    }
  }
  o += mb2[lane];
  return sv + o;
}

// ---------------- slots init (+ first q, + zero num/den) ----------------
__global__ __launch_bounds__(256) void k_init_slots_q(
  const float* __restrict__ mu, const float* __restrict__ sigma,
  const float* __restrict__ noise, float* __restrict__ slots,
  const float* __restrict__ Wq, const float* __restrict__ bq,
  const float* __restrict__ g_sl, const float* __restrict__ b_sl,
  const float* __restrict__ wkT, const float* __restrict__ bk,
  float* __restrict__ qout, float* __restrict__ qkb, float* __restrict__ qbb,
  float* __restrict__ num, float* __restrict__ den, const int do_qk)
{
  const int tid = blockIdx.x*256 + threadIdx.x;   // grid 56*256 = 14336 exact
  const int ri = tid>>6, lane = tid&63;
  const float sv = mu[lane] + sigma[lane] * noise[tid];
  slots[tid] = sv;
  num[tid] = 0.f;
  if (tid < 224) den[tid] = 0.f;
  q_from_slots(sv, ri, lane, Wq, bq, g_sl, b_sl, wkT, bk, qout, qkb, qbb, do_qk);
}

// ---------------- Wk transpose: wkT[e][d] = Wk[d][e] (once) ----------------
__global__ __launch_bounds__(256) void k_wkt(const float* __restrict__ Wk, float* __restrict__ wkT){
  const int i = blockIdx.x*256 + threadIdx.x;     // grid 16*256 = 4096 exact
  const int e = i>>6, d = i&63;
  wkT[i] = Wk[d*64 + e];
}

// ================= FAST PATH iter0: LN-fused attention (verified r7) =================
// grid = 32 b x 128 ch (128 keys/block). Reads x fp32, LN in-register, stages
// swizzled LDS + writes x̂ back to global. Partials: 128 chunks/row.
__global__ __launch_bounds__(256) void k_attn8(
  const float* __restrict__ x, u16* xg,
  const float* __restrict__ g_in, const float* __restrict__ b_in,
  const float* __restrict__ qkb, const float* __restrict__ qbb,
  float* __restrict__ pnum, float* __restrict__ pden)
{
  __shared__ __align__(16) u16   xs[128*64];      // 16 KB swizzled x̂ tile
  __shared__ __align__(16) u16   atb[7*AP6];      // bf16 attn weights
  __shared__ __align__(16) float dlds[128*9];     // dots (stride-9 pad)
  __shared__ float qbs[7];
  __shared__ float den_s[7];
  const int t = threadIdx.x;
  const int b = blockIdx.x >> 7, ch = blockIdx.x & 127;
  const int wid = t>>6, lane = t&63;
  const int m15 = lane&15, g4 = lane>>4;

  if (t < 7){ qbs[t] = qbb[b*7+t]; den_s[t] = 0.f; }
  // qk B-frags (slot n = m15, dims f*32 + g4*8 + j), slots 7..15 zero
  bf16x8 qf[2];
  #pragma unroll
  for (int f=0; f<2; ++f){
    float tmp[8];
    if (m15 < 7){ ld8(qkb + b*448 + m15*64 + f*32 + g4*8, tmp); }
    else {
      #pragma unroll
      for (int j=0;j<8;++j) tmp[j]=0.f;
    }
    #pragma unroll
    for (int j=0;j<8;++j) qf[f][j] = (__bf16)tmp[j];
  }

  // ---- fp32 read + in-register LayerNorm (k_kv pattern) ----
  {
    float gf[16], bfv[16];
    ld8(g_in + g4*8, gf);  ld8(g_in + 32 + g4*8, gf+8);
    ld8(b_in + g4*8, bfv); ld8(b_in + 32 + g4*8, bfv+8);
    #pragma unroll
    for (int p=0;p<2;++p){
      const int rl = p*64 + wid*16 + m15;       // local row 0..127, each once
      const long grow = (long)b*N_ + ch*128 + rl;
      const float* xr = x + grow*64;
      float xf[16];
      ld8(xr + g4*8, xf); ld8(xr + 32 + g4*8, xf+8);
      float s=0.f, ss=0.f;
      #pragma unroll
      for (int i=0;i<16;++i){ s += xf[i]; ss += xf[i]*xf[i]; }
      s  += __shfl_xor(s,16);  s  += __shfl_xor(s,32);
      ss += __shfl_xor(ss,16); ss += __shfl_xor(ss,32);
      const float mean = s*(1.f/64.f);
      const float rstd = rsqrtf(ss*(1.f/64.f) - mean*mean + 1e-5f);
      unsigned pw[8];
      #pragma unroll
      for (int j=0;j<8;++j){
        const u16 lo = f2b((xf[2*j]  -mean)*rstd*gf[2*j]   + bfv[2*j]);
        const u16 hi = f2b((xf[2*j+1]-mean)*rstd*gf[2*j+1] + bfv[2*j+1]);
        pw[j] = (unsigned)lo | ((unsigned)hi<<16);
      }
      *(uint4*)&xs[rl*64 + (((g4  ) ^ (rl&7))<<3)] = make_uint4(pw[0],pw[1],pw[2],pw[3]);
      *(uint4*)&xs[rl*64 + (((4+g4) ^ (rl&7))<<3)] = make_uint4(pw[4],pw[5],pw[6],pw[7]);
    }
  }
  __syncthreads();

  // coalesced global writeback of x̂ for iters 1-2 (inverse-swizzle read)
  {
    u16* gb = xg + ((long)b*N_ + ch*128)*64;
    #pragma unroll
    for (int p=0;p<4;++p){
      const int r = p*32 + (t>>3), c = t&7;
      const uint4 v = *(const uint4*)&xs[r*64 + ((c ^ (r&7))<<3)];
      *(uint4*)(gb + r*64 + c*8) = v;
    }
  }

  // ---- phase A: dots[key][slot] via MFMA ----
  #pragma unroll
  for (int mt=0; mt<2; ++mt){
    const int kr = (wid<<5) + (mt<<4) + m15;      // A: m=key
    f32x4 dacc = {0.f,0.f,0.f,0.f};
    #pragma unroll
    for (int f=0; f<2; ++f){
      const int c = (f<<2) + g4;                  // 16B chunk = dim/8
      const uint4 aw = *(const uint4*)&xs[kr*64 + ((c ^ (kr&7))<<3)];
      dacc = __builtin_amdgcn_mfma_f32_16x16x32_bf16(
               __builtin_bit_cast(bf16x8, aw), qf[f], dacc, 0,0,0);
    }
    if (m15 < 7){                                 // C: col=slot, row=key in 16
      const int krow = (wid<<5) + (mt<<4) + (g4<<2);
      #pragma unroll
      for (int r=0;r<4;++r) dlds[(krow+r)*9 + m15] = dacc[r];
    }
  }
  __syncthreads();

  // ---- per-key softmax over 7 slots (threads 0..127) ----
  if (t < 128){
    float acc[7];
    #pragma unroll
    for (int i=0;i<7;++i) acc[i] = (dlds[t*9+i] + qbs[i]) * SCALE_;
    float mx = -1e30f;
    #pragma unroll
    for (int i=0;i<7;++i) mx = fmaxf(mx, acc[i]);
    float e[7]; float sum = 0.f;
    #pragma unroll
    for (int i=0;i<7;++i){ e[i] = __expf(acc[i]-mx); sum += e[i]; }
    const float inv = 1.f/sum;
    float dsum[7];
    #pragma unroll
    for (int i=0;i<7;++i){
      const u16 rb = f2b(e[i]*inv + 1e-8f);
      atb[i*AP6 + t] = rb;
      dsum[i] = b2f(rb);            // den from the SAME rounded weights as num
    }
    #pragma unroll
    for (int i=0;i<7;++i){
      #pragma unroll
      for (int off=1; off<64; off<<=1) dsum[i] += __shfl_xor(dsum[i], off);
    }
    if (lane == 0){
      #pragma unroll
      for (int i=0;i<7;++i) atomicAdd(&den_s[i], dsum[i]);   // LDS atomic only
    }
  }
  __syncthreads();

  // ---- phase B: num^T[dim][slot] += x̂^T[dim][key] @ attn^T[key][slot] ----
  const int dim2 = ((wid<<4) + m15) << 1;   // byte col of this lane's A-dim
  f32x4 accv = {0.f,0.f,0.f,0.f};
  #pragma unroll
  for (int ks=0; ks<4; ++ks){
    const int kbase = (ks<<5) + (g4<<3);    // key base, multiple of 8
    const unsigned a0 = xs[(kbase+0)*64 + ((dim2 ^ (0<<4))>>1)];
    const unsigned a1 = xs[(kbase+1)*64 + ((dim2 ^ (1<<4))>>1)];
    const unsigned a2 = xs[(kbase+2)*64 + ((dim2 ^ (2<<4))>>1)];
    const unsigned a3 = xs[(kbase+3)*64 + ((dim2 ^ (3<<4))>>1)];
    const unsigned a4 = xs[(kbase+4)*64 + ((dim2 ^ (4<<4))>>1)];
    const unsigned a5 = xs[(kbase+5)*64 + ((dim2 ^ (5<<4))>>1)];
    const unsigned a6 = xs[(kbase+6)*64 + ((dim2 ^ (6<<4))>>1)];
    const unsigned a7 = xs[(kbase+7)*64 + ((dim2 ^ (7<<4))>>1)];
    const uint4 aw = make_uint4(a0|(a1<<16), a2|(a3<<16), a4|(a5<<16), a6|(a7<<16));
    const bf16x8 af = __builtin_bit_cast(bf16x8, aw);
    uint4 bw = make_uint4(0u,0u,0u,0u);
    if (m15 < 7) bw = *(const uint4*)&atb[m15*AP6 + kbase];
    const bf16x8 bfv = __builtin_bit_cast(bf16x8, bw);
    accv = __builtin_amdgcn_mfma_f32_16x16x32_bf16(af, bfv, accv, 0,0,0);
  }

  // ---- plain-store partials (128 chunks/row) ----
  if (m15 < 7){
    float* np = &pnum[(((long)b*7 + m15)*128 + ch)*64 + (wid<<4) + (g4<<2)];
    #pragma unroll
    for (int r=0;r<4;++r) np[r] = accv[r];
  }
  if (t < 7) pden[(b*7+t)*128 + ch] = den_s[t];
}

// ================= FAST PATH iters 1-2: double-buffered streaming (new) ========
// grid = 32 b x 64 ch (256 keys/block, 2 tiles of 128, dbuf LDS). All 8 staging
// loads in flight at block start (T14); phases identical to attn8. Partials:
// 64 chunks/row.
__global__ __launch_bounds__(256) void k_attn9(
  const u16* __restrict__ xln, const float* __restrict__ qkb, const float* __restrict__ qbb,
  float* __restrict__ pnum, float* __restrict__ pden)
{
  __shared__ __align__(16) u16   xs[2][128*64];   // 2 x 16 KB swizzled x̂ tiles
  __shared__ __align__(16) u16   atb[7*AP6];
  __shared__ __align__(16) float dlds[128*9];
  __shared__ float qbs[7];
  __shared__ float den_s[7];
  const int t = threadIdx.x;
  const int b = blockIdx.x >> 6, ch = blockIdx.x & 63;
  const int wid = t>>6, lane = t&63;
  const int m15 = lane&15, g4 = lane>>4;

  // ---- issue all 8 staging loads first (both tiles in flight) ----
  const u16* gbase = xln + ((long)b*N_ + ch*256)*64;
  uint4 s0[4], s1[4];
  #pragma unroll
  for (int p=0;p<4;++p) s0[p] = *(const uint4*)(gbase + p*2048 + t*8);
  #pragma unroll
  for (int p=0;p<4;++p) s1[p] = *(const uint4*)(gbase + 8192 + p*2048 + t*8);

  if (t < 7){ qbs[t] = qbb[b*7+t]; den_s[t] = 0.f; }
  bf16x8 qf[2];
  #pragma unroll
  for (int f=0; f<2; ++f){
    float tmp[8];
    if (m15 < 7){ ld8(qkb + b*448 + m15*64 + f*32 + g4*8, tmp); }
    else {
      #pragma unroll
      for (int j=0;j<8;++j) tmp[j]=0.f;
    }
    #pragma unroll
    for (int j=0;j<8;++j) qf[f][j] = (__bf16)tmp[j];
  }

  #pragma unroll
  for (int p=0;p<4;++p)
    *(uint4*)&xs[0][(p*32 + (t>>3))*64 + (((t&7) ^ ((t>>3)&7))<<3)] = s0[p];
  #pragma unroll
  for (int p=0;p<4;++p)
    *(uint4*)&xs[1][(p*32 + (t>>3))*64 + (((t&7) ^ ((t>>3)&7))<<3)] = s1[p];
  __syncthreads();

  const int dim2 = ((wid<<4) + m15) << 1;
  f32x4 accv = {0.f,0.f,0.f,0.f};

  // ---- A(0) ----
  #pragma unroll
  for (int mt=0; mt<2; ++mt){
    const int kr = (wid<<5) + (mt<<4) + m15;
    f32x4 dacc = {0.f,0.f,0.f,0.f};
    #pragma unroll
    for (int f=0; f<2; ++f){
      const int c = (f<<2) + g4;
      const uint4 aw = *(const uint4*)&xs[0][kr*64 + ((c ^ (kr&7))<<3)];
      dacc = __builtin_amdgcn_mfma_f32_16x16x32_bf16(
               __builtin_bit_cast(bf16x8, aw), qf[f], dacc, 0,0,0);
    }
    if (m15 < 7){
      const int krow = (wid<<5) + (mt<<4) + (g4<<2);
      #pragma unroll
      for (int r=0;r<4;++r) dlds[(krow+r)*9 + m15] = dacc[r];
    }
  }
  __syncthreads();

  // ---- softmax(0) ----
  if (t < 128){
    float acc[7];
    #pragma unroll
    for (int i=0;i<7;++i) acc[i] = (dlds[t*9+i] + qbs[i]) * SCALE_;
    float mx = -1e30f;
    #pragma unroll
    for (int i=0;i<7;++i) mx = fmaxf(mx, acc[i]);
    float e[7]; float sum = 0.f;
    #pragma unroll
    for (int i=0;i<7;++i){ e[i] = __expf(acc[i]-mx); sum += e[i]; }
    const float inv = 1.f/sum;
    float dsum[7];
    #pragma unroll
    for (int i=0;i<7;++i){
      const u16 rb = f2b(e[i]*inv + 1e-8f);
      atb[i*AP6 + t] = rb;
      dsum[i] = b2f(rb);
    }
    #pragma unroll
    for (int i=0;i<7;++i){
      #pragma unroll
      for (int off=1; off<64; off<<=1) dsum[i] += __shfl_xor(dsum[i], off);
    }
    if (lane == 0){
      #pragma unroll
      for (int i=0;i<7;++i) atomicAdd(&den_s[i], dsum[i]);
    }
  }
  __syncthreads();

  // ---- B(0) (reads xs[0]+atb) in parallel with A(1) (reads xs[1], writes dlds) ----
  #pragma unroll
  for (int ks=0; ks<4; ++ks){
    const int kbase = (ks<<5) + (g4<<3);
    const unsigned a0 = xs[0][(kbase+0)*64 + ((dim2 ^ (0<<4))>>1)];
    const unsigned a1 = xs[0][(kbase+1)*64 + ((dim2 ^ (1<<4))>>1)];
    const unsigned a2 = xs[0][(kbase+2)*64 + ((dim2 ^ (2<<4))>>1)];
    const unsigned a3 = xs[0][(kbase+3)*64 + ((dim2 ^ (3<<4))>>1)];
    const unsigned a4 = xs[0][(kbase+4)*64 + ((dim2 ^ (4<<4))>>1)];
    const unsigned a5 = xs[0][(kbase+5)*64 + ((dim2 ^ (5<<4))>>1)];
    const unsigned a6 = xs[0][(kbase+6)*64 + ((dim2 ^ (6<<4))>>1)];
    const unsigned a7 = xs[0][(kbase+7)*64 + ((dim2 ^ (7<<4))>>1)];
    const uint4 aw = make_uint4(a0|(a1<<16), a2|(a3<<16), a4|(a5<<16), a6|(a7<<16));
    const bf16x8 af = __builtin_bit_cast(bf16x8, aw);
    uint4 bw = make_uint4(0u,0u,0u,0u);
    if (m15 < 7) bw = *(const uint4*)&atb[m15*AP6 + kbase];
    const bf16x8 bfv = __builtin_bit_cast(bf16x8, bw);
    accv = __builtin_amdgcn_mfma_f32_16x16x32_bf16(af, bfv, accv, 0,0,0);
  }
  #pragma unroll
  for (int mt=0; mt<2; ++mt){
    const int kr = (wid<<5) + (mt<<4) + m15;
    f32x4 dacc = {0.f,0.f,0.f,0.f};
    #pragma unroll
    for (int f=0; f<2; ++f){
      const int c = (f<<2) + g4;
      const uint4 aw = *(const uint4*)&xs[1][kr*64 + ((c ^ (kr&7))<<3)];
      dacc = __builtin_amdgcn_mfma_f32_16x16x32_bf16(
               __builtin_bit_cast(bf16x8, aw), qf[f], dacc, 0,0,0);
    }
    if (m15 < 7){
      const int krow = (wid<<5) + (mt<<4) + (g4<<2);
      #pragma unroll
      for (int r=0;r<4;++r) dlds[(krow+r)*9 + m15] = dacc[r];
    }
  }
  __syncthreads();

  // ---- softmax(1) ----
  if (t < 128){
    float acc[7];
    #pragma unroll
    for (int i=0;i<7;++i) acc[i] = (dlds[t*9+i] + qbs[i]) * SCALE_;
    float mx = -1e30f;
    #pragma unroll
    for (int i=0;i<7;++i) mx = fmaxf(mx, acc[i]);
    float e[7]; float sum = 0.f;
    #pragma unroll
    for (int i=0;i<7;++i){ e[i] = __expf(acc[i]-mx); sum += e[i]; }
    const float inv = 1.f/sum;
    float dsum[7];
    #pragma unroll
    for (int i=0;i<7;++i){
      const u16 rb = f2b(e[i]*inv + 1e-8f);
      atb[i*AP6 + t] = rb;
      dsum[i] = b2f(rb);
    }
    #pragma unroll
    for (int i=0;i<7;++i){
      #pragma unroll
      for (int off=1; off<64; off<<=1) dsum[i] += __shfl_xor(dsum[i], off);
    }
    if (lane == 0){
      #pragma unroll
      for (int i=0;i<7;++i) atomicAdd(&den_s[i], dsum[i]);
    }
  }
  __syncthreads();

  // ---- B(1) ----
  #pragma unroll
  for (int ks=0; ks<4; ++ks){
    const int kbase = (ks<<5) + (g4<<3);
    const unsigned a0 = xs[1][(kbase+0)*64 + ((dim2 ^ (0<<4))>>1)];
    const unsigned a1 = xs[1][(kbase+1)*64 + ((dim2 ^ (1<<4))>>1)];
    const unsigned a2 = xs[1][(kbase+2)*64 + ((dim2 ^ (2<<4))>>1)];
    const unsigned a3 = xs[1][(kbase+3)*64 + ((dim2 ^ (3<<4))>>1)];
    const unsigned a4 = xs[1][(kbase+4)*64 + ((dim2 ^ (4<<4))>>1)];
    const unsigned a5 = xs[1][(kbase+5)*64 + ((dim2 ^ (5<<4))>>1)];
    const unsigned a6 = xs[1][(kbase+6)*64 + ((dim2 ^ (6<<4))>>1)];
    const unsigned a7 = xs[1][(kbase+7)*64 + ((dim2 ^ (7<<4))>>1)];
    const uint4 aw = make_uint4(a0|(a1<<16), a2|(a3<<16), a4|(a5<<16), a6|(a7<<16));
    const bf16x8 af = __builtin_bit_cast(bf16x8, aw);
    uint4 bw = make_uint4(0u,0u,0u,0u);
    if (m15 < 7) bw = *(const uint4*)&atb[m15*AP6 + kbase];
    const bf16x8 bfv = __builtin_bit_cast(bf16x8, bw);
    accv = __builtin_amdgcn_mfma_f32_16x16x32_bf16(af, bfv, accv, 0,0,0);
  }

  // ---- plain-store partials (64 chunks/row) ----
  if (m15 < 7){
    float* np = &pnum[(((long)b*7 + m15)*64 + ch)*64 + (wid<<4) + (g4<<2)];
    #pragma unroll
    for (int r=0;r<4;++r) np[r] = accv[r];
  }
  if (t < 7) pden[(b*7+t)*64 + ch] = den_s[t];
}

// ================= FALLBACK: fused attention (verified) =================
__global__ __launch_bounds__(256) void k_attn_fused(
  const float* __restrict__ x,
  const float* __restrict__ Wk, const float* __restrict__ bk,
  const float* __restrict__ Wv, const float* __restrict__ bv,
  const float* __restrict__ g_in, const float* __restrict__ b_in,
  const float* __restrict__ qbuf, float* __restrict__ num, float* __restrict__ den)
{
  __shared__ __align__(16) u16   tile[TILE*TPAD];
  __shared__ __align__(16) float qs[7*64];
  __shared__ __align__(16) float at[7*TILE];
  const int t = threadIdx.x;
  const int b = blockIdx.x >> 6, ch = blockIdx.x & 63;
  for (int i=t; i<448; i+=256) qs[i] = qbuf[b*448 + i];
  const int wid = t>>6, lane = t&63;
  const int m = lane & 15, q4 = lane >> 4;
  float gf[16], bfv[16];
  ld8(g_in + q4*8, gf);  ld8(g_in + 32 + q4*8, gf+8);
  ld8(b_in + q4*8, bfv); ld8(b_in + 32 + q4*8, bfv+8);
  const int i0 = wid*2, i1 = wid*2+1;
  float n0=0.f, n1=0.f, d0=0.f, d1=0.f;

  for (int tl=0; tl<2; ++tl){
    const long j0 = (long)ch*256 + tl*TILE;
    const long rowbase = (long)b*N_ + j0 + (long)wid*32;
    __syncthreads();
    bf16x8 af[2][2];
    #pragma unroll
    for (int rg=0; rg<2; ++rg){
      const float* xr = x + (rowbase + rg*16 + m)*64;
      float xf[16];
      ld8(xr + q4*8, xf); ld8(xr + 32 + q4*8, xf+8);
      float s=0.f, ss=0.f;
      #pragma unroll
      for (int i=0;i<16;++i){ s += xf[i]; ss += xf[i]*xf[i]; }
      s  += __shfl_xor(s,16);  s  += __shfl_xor(s,32);
      ss += __shfl_xor(ss,16); ss += __shfl_xor(ss,32);
      const float mean = s*(1.f/64.f);
      const float rstd = rsqrtf(ss*(1.f/64.f) - mean*mean + 1e-5f);
      #pragma unroll
      for (int j=0;j<8;++j){
        af[rg][0][j] = (__bf16)((xf[j]  -mean)*rstd*gf[j]   + bfv[j]);
        af[rg][1][j] = (__bf16)((xf[8+j]-mean)*rstd*gf[8+j] + bfv[8+j]);
      }
    }
    {
      bf16x8 w0[4], w1[4]; float bc[4];
      #pragma unroll
      for (int cg=0; cg<4; ++cg){
        const int n = cg*16 + m;
        w0[cg] = frag8(Wk + n*64 + q4*8);
        w1[cg] = frag8(Wk + n*64 + 32 + q4*8);
        bc[cg] = bk[n];
      }
      #pragma unroll
      for (int rg=0; rg<2; ++rg){
        #pragma unroll
        for (int cg=0; cg<4; ++cg){
          f32x4 acc = {0.f,0.f,0.f,0.f};
          acc = __builtin_amdgcn_mfma_f32_16x16x32_bf16(af[rg][0], w0[cg], acc, 0,0,0);
          acc = __builtin_amdgcn_mfma_f32_16x16x32_bf16(af[rg][1], w1[cg], acc, 0,0,0);
          const int col = cg*16 + m;
          #pragma unroll
          for (int r=0;r<4;++r)
            tile[(wid*32 + rg*16 + q4*4 + r)*TPAD + col] = f2b(acc[r] + bc[cg]);
        }
      }
    }
    __syncthreads();
    if (t < TILE){
      float acc[7];
      #pragma unroll
      for (int i=0;i<7;++i) acc[i]=0.f;
      const unsigned* krow = (const unsigned*)&tile[t*TPAD];
      for (int wq=0; wq<8; ++wq){
        const unsigned k0 = krow[wq*4+0], k1 = krow[wq*4+1], k2 = krow[wq*4+2], k3 = krow[wq*4+3];
        float kf[8];
        kf[0]=blo(k0); kf[1]=bhi(k0); kf[2]=blo(k1); kf[3]=bhi(k1);
        kf[4]=blo(k2); kf[5]=bhi(k2); kf[6]=blo(k3); kf[7]=bhi(k3);
        #pragma unroll
        for (int i=0;i<7;++i){
          const float4 qa = *(const float4*)&qs[i*64 + wq*8];
          const float4 qb = *(const float4*)&qs[i*64 + wq*8 + 4];
          acc[i] += kf[0]*qa.x + kf[1]*qa.y + kf[2]*qa.z + kf[3]*qa.w
                  + kf[4]*qb.x + kf[5]*qb.y + kf[6]*qb.z + kf[7]*qb.w;
        }
      }
      float mx = -1e30f;
      #pragma unroll
      for (int i=0;i<7;++i){ acc[i] *= SCALE_; mx = fmaxf(mx, acc[i]); }
      float e[7]; float sum = 0.f;
      #pragma unroll
      for (int i=0;i<7;++i){ e[i] = __expf(acc[i]-mx); sum += e[i]; }
      const float inv = 1.f/sum;
      #pragma unroll
      for (int i=0;i<7;++i) at[i*TILE + t] = e[i]*inv + 1e-8f;
    }
    __syncthreads();
    {
      bf16x8 w0[4], w1[4]; float bc[4];
      #pragma unroll
      for (int cg=0; cg<4; ++cg){
        const int n = cg*16 + m;
        w0[cg] = frag8(Wv + n*64 + q4*8);
        w1[cg] = frag8(Wv + n*64 + 32 + q4*8);
        bc[cg] = bv[n];
      }
      #pragma unroll
      for (int rg=0; rg<2; ++rg){
        #pragma unroll
        for (int cg=0; cg<4; ++cg){
          f32x4 acc = {0.f,0.f,0.f,0.f};
          acc = __builtin_amdgcn_mfma_f32_16x16x32_bf16(af[rg][0], w0[cg], acc, 0,0,0);
          acc = __builtin_amdgcn_mfma_f32_16x16x32_bf16(af[rg][1], w1[cg], acc, 0,0,0);
          const int col = cg*16 + m;
          #pragma unroll
          for (int r=0;r<4;++r)
            tile[(wid*32 + rg*16 + q4*4 + r)*TPAD + col] = f2b(acc[r] + bc[cg]);
        }
      }
    }
    __syncthreads();
    #pragma unroll 4
    for (int j=0;j<TILE;++j){
      const unsigned vw = ((const unsigned*)&tile[j*TPAD])[lane>>1];
      const float vf = (lane&1) ? bhi(vw) : blo(vw);
      const float a0v = at[i0*TILE+j];
      n0 += a0v*vf; d0 += a0v;
      if (i1 < 7){ const float a1v = at[i1*TILE+j]; n1 += a1v*vf; d1 += a1v; }
    }
  }
  atomicAdd(&num[(b*7+i0)*64 + lane], n0);
  if (lane==0) atomicAdd(&den[b*7+i0], d0);
  if (i1 < 7){
    atomicAdd(&num[(b*7+i1)*64 + lane], n1);
    if (lane==0) atomicAdd(&den[b*7+i1], d1);
  }
}

// ---------------- per-iter: updates -> GRU -> residual MLP (+ next q) ----------------
__global__ __launch_bounds__(256) void k_gru_mlp(
  float* __restrict__ num, float* __restrict__ den,
  const float* __restrict__ pnum, const float* __restrict__ pden,
  float* __restrict__ slots,
  const float* __restrict__ Wv, const float* __restrict__ bv,
  const float* __restrict__ Wih, const float* __restrict__ Whh,
  const float* __restrict__ bih, const float* __restrict__ bhh,
  const float* __restrict__ mW1, const float* __restrict__ mb1,
  const float* __restrict__ mW2, const float* __restrict__ mb2,
  const float* __restrict__ g_ml, const float* __restrict__ b_ml,
  const float* __restrict__ Wq, const float* __restrict__ bq,
  const float* __restrict__ g_sl, const float* __restrict__ b_sl,
  const float* __restrict__ wkT, const float* __restrict__ bk,
  float* __restrict__ qout, float* __restrict__ qkb, float* __restrict__ qbb,
  float* __restrict__ outp,
  const int write_out, const int nch, const int do_q, const int do_qk)
{
  const int tid = blockIdx.x*256 + threadIdx.x;  // grid 56*256: 224 waves = 224 rows
  const int ri = tid>>6, lane = tid&63;
  float a;
  const int fastmode = (nch > 0);
  if (fastmode){
    // reduce the nch per-chunk partials (plain loads, no atomics upstream)
    float asum = 0.f;
    const float* pn = pnum + (long)ri*nch*64 + lane;
    #pragma unroll 8
    for (int c=0;c<nch;++c) asum += pn[c*64];
    float v;
    if (nch == 128) v = pden[ri*128 + lane] + pden[ri*128 + 64 + lane];
    else            v = pden[ri*64 + lane];
    #pragma unroll
    for (int off=1; off<64; off<<=1) v += __shfl_xor(v, off);
    const float dn = v;
    a = (dn > 0.f) ? (asum / dn) : 0.f;
  } else {
    const float dn = den[ri];
    a = (dn > 0.f) ? (num[tid] / dn) : 0.f;
    num[tid] = 0.f;                 // re-zero for next iter
    if (lane == 0) den[ri] = 0.f;
  }
  float u;
  if (fastmode){
    float acc = 0.f;
    for (int e8=0; e8<8; ++e8){
      float f[8]; ld8(Wv + lane*64 + e8*8, f);
      #pragma unroll
      for (int j=0;j<8;++j) acc += __shfl(a, e8*8+j) * f[j];
    }
    u = acc + bv[lane];
  } else {
    u = a;
  }
  const float h = slots[tid];
  const float res = gru_mlp_row(u, h, lane, Wih, Whh, bih, bhh,
                                mW1, mb1, mW2, mb2, g_ml, b_ml);
  slots[tid] = res;
  if (write_out) outp[tid] = res;
  if (do_q)
    q_from_slots(res, ri, lane, Wq, bq, g_sl, b_sl, wkT, bk, qout, qkb, qbb, do_qk);
}

extern "C" void kernel_launch(void* const* d_in, const int* in_sizes, int n_in,
                              void* d_out, int out_size, void* d_ws, size_t ws_size,
                              hipStream_t stream)
{
  float* outp = (float*)d_out;
  static const int EXP[24] = {33554432,14336,64,64, 4096,64, 4096,64, 4096,64,
                              12288,12288,192,192, 8192,128, 8192,64,
                              64,64, 64,64, 64,64};
  if (n_in != 24){ k_marker<<<56,256,0,stream>>>(outp, out_size, 30.f); return; }
  for (int i=0;i<24;++i)
    if (in_sizes[i] != EXP[i]){ k_marker<<<56,256,0,stream>>>(outp, out_size, 40.f+(float)i); return; }
  if (out_size != 14336){ k_marker<<<56,256,0,stream>>>(outp, out_size, 33.f); return; }
  if (ws_size < 300000){ k_marker<<<56,256,0,stream>>>(outp, out_size, 35.f); return; }

  const float* inputs = (const float*)d_in[0];
  const float* noise  = (const float*)d_in[1];
  const float* mu     = (const float*)d_in[2];
  const float* sigma  = (const float*)d_in[3];
  const float* Wq  = (const float*)d_in[4];  const float* bq  = (const float*)d_in[5];
  const float* Wk  = (const float*)d_in[6];  const float* bk  = (const float*)d_in[7];
  const float* Wv  = (const float*)d_in[8];  const float* bv  = (const float*)d_in[9];
  const float* Wih = (const float*)d_in[10]; const float* Whh = (const float*)d_in[11];
  const float* bih = (const float*)d_in[12]; const float* bhh = (const float*)d_in[13];
  const float* mW1 = (const float*)d_in[14]; const float* mb1 = (const float*)d_in[15];
  const float* mW2 = (const float*)d_in[16]; const float* mb2 = (const float*)d_in[17];
  const float* g_in = (const float*)d_in[18]; const float* b_in = (const float*)d_in[19];
  const float* g_sl = (const float*)d_in[20]; const float* b_sl = (const float*)d_in[21];
  const float* g_ml = (const float*)d_in[22]; const float* b_ml = (const float*)d_in[23];

  char* ws = (char*)d_ws;
  float* slots = (float*)ws;                         // 14336 f
  float* qbuf  = (float*)(ws + 57344);               // 14336 f (plain q, fallback)
  float* qkb   = (float*)(ws + 114688);              // 14336 f (q @ Wk)
  float* num   = (float*)(ws + 172032);              // 14336 f (fallback)
  float* den   = (float*)(ws + 229376);              // 224 f (fallback)
  float* qbb   = (float*)(ws + 230272);              // 224 f (q . bk)
  float* wkT   = (float*)(ws + 231168);              // 4096 f (Wk^T)
  float* pnum  = (float*)(ws + 247808);              // 1,835,008 f (7.34 MB partial num)
  float* pden  = (float*)(ws + 7587840);             // 28,672 f (partial den)
  u16* xln     = (u16*)(ws + 7702528);               // 33.5M bf16 (67.1 MB)
  const bool fast = (ws_size >= (size_t)7702528 + 67108864ull);

  if (fast)
    k_wkt<<<16,256,0,stream>>>(Wk, wkT);
  k_init_slots_q<<<56,256,0,stream>>>(mu, sigma, noise, slots,
                                      Wq, bq, g_sl, b_sl, wkT, bk,
                                      qbuf, qkb, qbb, num, den, fast ? 1 : 0);
  if (fast){
    for (int it=0; it<3; ++it){
      if (it == 0)
        k_attn8<<<4096,256,0,stream>>>(inputs, xln, g_in, b_in,
                                       qkb, qbb, pnum, pden);
      else
        k_attn9<<<2048,256,0,stream>>>(xln, qkb, qbb, pnum, pden);
      k_gru_mlp<<<56,256,0,stream>>>(num, den, pnum, pden, slots, Wv, bv,
                                     Wih, Whh, bih, bhh,
                                     mW1, mb1, mW2, mb2, g_ml, b_ml,
                                     Wq, bq, g_sl, b_sl, wkT, bk,
                                     qbuf, qkb, qbb, outp,
                                     it==2 ? 1 : 0, it==0 ? 128 : 64,
                                     it<2 ? 1 : 0, it<2 ? 1 : 0);
    }
  } else {
    for (int it=0; it<3; ++it){
      k_attn_fused<<<2048,256,0,stream>>>(inputs, Wk, bk, Wv, bv, g_in, b_in, qbuf, num, den);
      k_gru_mlp<<<56,256,0,stream>>>(num, den, pnum, pden, slots, Wv, bv,
                                     Wih, Whh, bih, bhh,
                                     mW1, mb1, mW2, mb2, g_ml, b_ml,
                                     Wq, bq, g_sl, b_sl, wkT, bk,
                                     qbuf, qkb, qbb, outp,
                                     it==2 ? 1 : 0, 0,
                                     it<2 ? 1 : 0, 0);
    }
  }
}